// Round 13
// baseline (240.384 us; speedup 1.0000x reference)
//
#include <hip/hip_runtime.h>
#include <math.h>

#define BATCH 8
constexpr float DXC   = 2.0f/31.0f;
constexpr float DXDY  = DXC*DXC;
constexpr float SCALE = 0.125f;      // 1/sqrt(64), folded into M/u/v/c at reduce
constexpr float EPSC  = 1e-5f;
constexpr float SLOPEC= 0.01f;

// ---- workspace float offsets ----
#define OFF_LNP    0u         // 256
#define OFF_M      256u       // 16384
#define OFF_U      16640u     // 256
#define OFF_V      16896u     // 256
#define OFF_C      17152u     // 16
#define OFF_WSPART 17168u     // 4096 (4 ns-partials x 1024)
#define OFF_VIN    150288u    // 1048576
#define OFF_W      1198864u   // 1048576
#define OFF_WF     2247440u   // 1048576
#define OFF_GPA    3296016u   // 1048576  (gram partials A; reused as Pg ns0/1 at the end)
#define OFF_GSA    4344592u   // 16384
#define OFF_GPB    4360976u   // 1048576  (B; prep-partials live here pre-layer0)
#define OFF_GSB    5409552u   // 16384
#define OFF_P      5425936u   // 1048576  (Pg ns2/3)

// prep partial layout inside GPB: per (j,ch) stride 4352 = [4096 M][64 u][64 v][1 c][pad]
#define MP_STRIDE  4352

typedef short bf16x8 __attribute__((ext_vector_type(8)));
typedef float f32x4  __attribute__((ext_vector_type(4)));

struct MlpW {
  const float *kW0,*kb0,*kW1,*kb1,*kW2,*kb2;
  const float *fW0,*fb0,*fW1,*fb1,*fW2,*fb2;
  float *wo, *wfo;
};

__device__ __forceinline__ unsigned cvt2bf(float a, float b){
  unsigned r; asm("v_cvt_pk_bf16_f32 %0, %1, %2" : "=v"(r) : "v"(a), "v"(b)); return r;
}

__device__ __forceinline__ float lrelu(float x){ return fmaxf(x, SLOPEC*x); }

__device__ __forceinline__ float wsum64(float v){
  #pragma unroll
  for(int off=32; off; off>>=1) v += __shfl_xor(v, off);
  return v;
}

__device__ __forceinline__ float bcast(float v, int src){
  return __builtin_bit_cast(float,
    __builtin_amdgcn_readlane(__builtin_bit_cast(int, v), src));
}

// -------- one edge-MLP unit (which,i) over all 1024 j, by 4 waves (swid 0..3) ------
__device__ __forceinline__ void mlp_unit(const MlpW P, int unit, int swid, int lane)
{
  int which = unit>>10, i = unit&1023;
  const float* W0 = which? P.fW0:P.kW0; const float* b0 = which? P.fb0:P.kb0;
  const float* W1 = which? P.fW1:P.kW1; const float* b1 = which? P.fb1:P.kb1;
  const float* W2 = which? P.fW2:P.kW2; const float* b2 = which? P.fb2:P.kb2;
  float* outp = which? P.wfo : P.wo;
  int grp = lane>>4, jl = lane&15;
  float xi = -1.f + DXC*(float)(i>>5), yi = -1.f + DXC*(float)(i&31);
  float a0c[8], wxc[8], wyc[8];
  #pragma unroll
  for(int t=0;t<8;t++){
    int c = grp*8+t;
    float4 w0 = *(const float4*)(W0 + c*4);
    a0c[t] = w0.x*xi + w0.y*yi + b0[c];
    wxc[t] = w0.z; wyc[t] = w0.w;
  }
  bf16x8 afr[4];
  #pragma unroll
  for(int ot=0;ot<4;ot++){
    const float* src = W1 + (ot*16+jl)*32 + grp*8;
    uint4 p;
    p.x=cvt2bf(src[0],src[1]); p.y=cvt2bf(src[2],src[3]);
    p.z=cvt2bf(src[4],src[5]); p.w=cvt2bf(src[6],src[7]);
    afr[ot] = __builtin_bit_cast(bf16x8, p);
  }
  float b1v[16], w2v[16];
  #pragma unroll
  for(int ot=0;ot<4;ot++){
    #pragma unroll
    for(int r=0;r<4;r++){
      int o = ot*16 + grp*4 + r;
      b1v[ot*4+r] = b1[o];
      w2v[ot*4+r] = W2[o];
    }
  }
  float b2s = b2[0];
  f32x4 zz = {0.f,0.f,0.f,0.f};
  int jbase = swid*256;
  for(int jt=0;jt<16;jt++){
    int j0 = jbase + jt*16;
    int j  = j0 + jl;
    float xj = -1.f + DXC*(float)(j>>5), yj = -1.f + DXC*(float)(j&31);
    float h[8];
    #pragma unroll
    for(int t=0;t<8;t++){
      float p = a0c[t] + wxc[t]*xj + wyc[t]*yj;
      h[t] = fmaxf(p, SLOPEC*p);
    }
    uint4 hb;
    hb.x=cvt2bf(h[0],h[1]); hb.y=cvt2bf(h[2],h[3]);
    hb.z=cvt2bf(h[4],h[5]); hb.w=cvt2bf(h[6],h[7]);
    bf16x8 bfr = __builtin_bit_cast(bf16x8, hb);
    f32x4 d0 = __builtin_amdgcn_mfma_f32_16x16x32_bf16(afr[0], bfr, zz, 0,0,0);
    f32x4 d1 = __builtin_amdgcn_mfma_f32_16x16x32_bf16(afr[1], bfr, zz, 0,0,0);
    f32x4 d2 = __builtin_amdgcn_mfma_f32_16x16x32_bf16(afr[2], bfr, zz, 0,0,0);
    f32x4 d3 = __builtin_amdgcn_mfma_f32_16x16x32_bf16(afr[3], bfr, zz, 0,0,0);
    float part = 0.f;
    #pragma unroll
    for(int r=0;r<4;r++){
      float s0 = d0[r]+b1v[r];    part = fmaf(w2v[r],    fmaxf(s0,SLOPEC*s0), part);
      float s1 = d1[r]+b1v[4+r];  part = fmaf(w2v[4+r],  fmaxf(s1,SLOPEC*s1), part);
      float s2 = d2[r]+b1v[8+r];  part = fmaf(w2v[8+r],  fmaxf(s2,SLOPEC*s2), part);
      float s3 = d3[r]+b1v[12+r]; part = fmaf(w2v[12+r], fmaxf(s3,SLOPEC*s3), part);
    }
    part += __shfl_xor(part, 16);
    part += __shfl_xor(part, 32);
    if(lane<16) outp[i*1024 + j0 + lane] = part + b2s;
  }
}

// ------- first launch: prep PARTIALS (64 blocks, 16 hk each) + LN0 partials -------
__global__ __launch_bounds__(256) void k_pre(
    const float* __restrict__ xy,
    const float* __restrict__ Wq, const float* __restrict__ bq,
    const float* __restrict__ Wk, const float* __restrict__ bk,
    float* __restrict__ ws)
{
  __shared__ float red[8];
  int blk = blockIdx.x, tid = threadIdx.x;
  int lane = tid&63;
  int wid = __builtin_amdgcn_readfirstlane(tid>>6);
  if(blk < 64){
    int j = blk>>4, ch = blk&15;
    float mac[16], uac[16];
    #pragma unroll
    for(int r=0;r<16;r++){ mac[r]=0.f; uac[r]=0.f; }
    float vac=0.f, cac=0.f;
    #pragma unroll 4
    for(int hk=ch*16; hk<ch*16+16; hk++){
      const float* wqrow = Wq + ((size_t)j*256+hk)*64;
      const float* wkrow = Wk + ((size_t)j*256+hk)*64;
      float wkl = wkrow[lane];
      float bkk = bk[j*256+hk], bqk = bq[j*256+hk];
      #pragma unroll
      for(int r=0;r<16;r++){ float wq=wqrow[wid*16+r]; mac[r]+=wq*wkl; uac[r]+=wq*bkk; }
      vac += bqk*wkl; cac += bqk*bkk;
    }
    float* mp = ws + OFF_GPB + (size_t)(j*16+ch)*MP_STRIDE;
    #pragma unroll
    for(int r=0;r<16;r++) mp[(wid*16+r)*64+lane] = mac[r];
    if(lane==0){
      #pragma unroll
      for(int r=0;r<16;r++) mp[4096 + wid*16+r] = uac[r];
    }
    if(wid==0) mp[4160+lane] = vac;
    if(tid==0) mp[4224] = cac;
  } else {
    int bb = blk-64;                             // 128 blocks
    int b = bb>>4, seg = bb&15;
    const float4* x4 = (const float4*)(xy + (size_t)b*131072 + seg*8192);
    float s=0.f, ss=0.f;
    #pragma unroll
    for(int k2=0;k2<8;k2++){
      float4 v = x4[tid + k2*256];
      s  += v.x+v.y+v.z+v.w;
      ss += v.x*v.x+v.y*v.y+v.z*v.z+v.w*v.w;
    }
    s = wsum64(s); ss = wsum64(ss);
    if(lane==0){ red[wid]=s; red[4+wid]=ss; }
    __syncthreads();
    if(tid==0){
      ws[OFF_LNP + (b*16+seg)*2  ] = red[0]+red[1]+red[2]+red[3];
      ws[OFF_LNP + (b*16+seg)*2+1] = red[4]+red[5]+red[6]+red[7];
    }
  }
}

// ---------------- Gram of 64x64 LDS tiles (8 waves: 8 cols each) ----------------
__device__ __forceinline__ void gram_tile8(const float* sA, const float* sB,
    int wid, int lane, float* __restrict__ gp, float* __restrict__ gsp)
{
  float acc[8];
  #pragma unroll
  for(int q=0;q<8;q++) acc[q]=0.f;
  float gsa=0.f;
  for(int m=0;m<64;m++){
    const float4* cp = (const float4*)(sA + m*64 + wid*8);
    float bml = sB[m*64+lane];
    float4 a0=cp[0],a1=cp[1];
    acc[0]+=a0.x*bml; acc[1]+=a0.y*bml; acc[2]+=a0.z*bml; acc[3]+=a0.w*bml;
    acc[4]+=a1.x*bml; acc[5]+=a1.y*bml; acc[6]+=a1.z*bml; acc[7]+=a1.w*bml;
    gsa += bml;
  }
  #pragma unroll
  for(int q=0;q<8;q++) gp[(wid*8+q)*64+lane]=acc[q];
  if(wid==0) gsp[lane]=gsa;
}

// ---------------- T build from LDS Gram (8 waves: 8 rows each) ----------------
__device__ __forceinline__ void build_T8(const float* __restrict__ sG,
    const float* __restrict__ Mj, const float* __restrict__ uj,
    const float* __restrict__ vj, float cj, float gsl,
    int wid, int lane, float* __restrict__ sT, float* __restrict__ stv)
{
  float gv[64];
  #pragma unroll
  for(int c=0;c<64;c++) gv[c]=sG[c*64+lane];
  float tacc = cj*gsl;
  #pragma unroll
  for(int c=0;c<64;c++) tacc += vj[c]*gv[c];
  #pragma unroll
  for(int rr=0;rr<8;rr++){
    int r = wid*8+rr;
    const float* mrow = Mj + r*64;                // wave-uniform -> s_load
    float acc = uj[r]*gsl;
    #pragma unroll
    for(int c=0;c<64;c++) acc += mrow[c]*gv[c];
    sT[r*64+lane]=acc;
  }
  if(wid==0) stv[lane]=tacc;
}

// ------- LN0 apply + Gram (512 thr) + MLP ride-along + prep-reduce blocks ---------
__global__ __launch_bounds__(512) void k_ln0ag(const float* __restrict__ xy,
    const float* __restrict__ g, const float* __restrict__ bb,
    const float* __restrict__ lnp,
    float* __restrict__ Vin, float* __restrict__ Gpart, float* __restrict__ gspart,
    MlpW P, int mlp_off, float* __restrict__ ws)
{
  __shared__ float sV[4096];
  int blk = blockIdx.x;
  int tid = threadIdx.x, lane = tid&63;
  int wid = __builtin_amdgcn_readfirstlane(tid>>6);
  if(blk >= 598){
    // reduce prep partials -> Mg/ug/vg/cg (4 blocks)
    int j = blk-598;
    const float* mp0 = ws + OFF_GPB + (size_t)(j*16)*MP_STRIDE;
    for(int e=tid; e<1024; e+=512){
      float4 s={0,0,0,0};
      for(int ch=0; ch<16; ch++){
        float4 v = *(const float4*)&mp0[(size_t)ch*MP_STRIDE + e*4];
        s.x+=v.x; s.y+=v.y; s.z+=v.z; s.w+=v.w;
      }
      s.x*=SCALE; s.y*=SCALE; s.z*=SCALE; s.w*=SCALE;
      *(float4*)&ws[OFF_M + j*4096 + e*4] = s;
    }
    if(tid<64){
      float su=0.f, sv=0.f;
      for(int ch=0; ch<16; ch++){
        su += mp0[(size_t)ch*MP_STRIDE + 4096 + tid];
        sv += mp0[(size_t)ch*MP_STRIDE + 4160 + tid];
      }
      ws[OFF_U + j*64+tid] = su*SCALE;
      ws[OFF_V + j*64+tid] = sv*SCALE;
    }
    if(tid==0){
      float sc=0.f;
      for(int ch=0; ch<16; ch++) sc += mp0[(size_t)ch*MP_STRIDE + 4224];
      ws[OFF_C + j] = sc*SCALE;
    }
    return;
  }
  if(blk >= 256){
    mlp_unit(P, mlp_off + (blk-256)*2 + (wid>>2), wid&3, lane);
    return;
  }
  int b = blk>>5, ch = blk&31;
  float s=0.f, ss=0.f;
  #pragma unroll
  for(int k2=0;k2<16;k2++){ s += lnp[(b*16+k2)*2]; ss += lnp[(b*16+k2)*2+1]; }
  float mean = s*(1.0f/131072.0f);
  float var  = ss*(1.0f/131072.0f) - mean*mean;
  float inv  = 1.0f/sqrtf(var+EPSC);
  const float4* x4 = (const float4*)(xy + ((size_t)b*2048 + ch*64)*64);
  const float4* g4 = (const float4*)(g  + (size_t)ch*4096);
  const float4* b4 = (const float4*)(bb + (size_t)ch*4096);
  float4* vo4 = (float4*)(Vin + ((size_t)b*2048 + ch*64)*64);
  float4* sv4 = (float4*)sV;
  #pragma unroll
  for(int e=0;e<2;e++){
    int idx = tid + e*512;
    float4 xv=x4[idx], gv=g4[idx], bv=b4[idx];
    float4 r;
    r.x=(xv.x-mean)*inv*gv.x+bv.x;
    r.y=(xv.y-mean)*inv*gv.y+bv.y;
    r.z=(xv.z-mean)*inv*gv.z+bv.z;
    r.w=(xv.w-mean)*inv*gv.w+bv.w;
    vo4[idx]=r; sv4[idx]=r;
  }
  __syncthreads();
  gram_tile8(sV, sV, wid, lane, Gpart+((size_t)(b*32+ch))*4096, gspart+(b*32+ch)*64);
}

// -------- layer (512 threads) + MLP ride-along ----------
__global__ __launch_bounds__(512) void k_layer(
    float* __restrict__ Vin, const float* __restrict__ xy,
    const float* __restrict__ Gsrc, const float* __restrict__ gssrc,
    float* __restrict__ Gdst, float* __restrict__ gsdst,
    const float* __restrict__ Mg, const float* __restrict__ ug,
    const float* __restrict__ vg, const float* __restrict__ cg,
    const float* __restrict__ lng, const float* __restrict__ lnb,
    int j, int cross, MlpW P, int mlp_off)
{
  __shared__ float sV[4096];
  __shared__ float sT[4096];
  __shared__ float sG[4096];
  __shared__ float stv[64];
  int blk = blockIdx.x, tid = threadIdx.x;
  int lane = tid&63;
  int wid = __builtin_amdgcn_readfirstlane(tid>>6);
  if(blk >= 256){
    mlp_unit(P, mlp_off + (blk-256)*2 + (wid>>2), wid&3, lane);
    return;
  }
  int b = blk>>5, ch = blk&31;
  float* vbase = Vin + ((size_t)b*2048 + ch*64)*64;
  {
    const float4* vb4=(const float4*)vbase;
    float4* sv4=(float4*)sV;
    #pragma unroll
    for(int e=0;e<2;e++) sv4[tid+e*512]=vb4[tid+e*512];
  }
  {
    float4 a0={0,0,0,0},a1={0,0,0,0};
    const float4* gp4 = (const float4*)(Gsrc + (size_t)b*32*4096) + tid*2;
    for(int c=0;c<32;c++){
      const float4* p = gp4 + c*1024;
      float4 v0=p[0],v1=p[1];
      a0.x+=v0.x;a0.y+=v0.y;a0.z+=v0.z;a0.w+=v0.w;
      a1.x+=v1.x;a1.y+=v1.y;a1.z+=v1.z;a1.w+=v1.w;
    }
    float4* sg4=(float4*)sG + tid*2;
    sg4[0]=a0; sg4[1]=a1;
  }
  float gsl=0.f;
  for(int c=0;c<32;c++) gsl += gssrc[(b*32+c)*64+lane];
  __syncthreads();
  build_T8(sG, Mg+j*4096, ug+j*64, vg+j*64, cg[j], gsl, wid, lane, sT, stv);
  __syncthreads();
  float Tcol[64];
  #pragma unroll
  for(int c=0;c<64;c++) Tcol[c]=sT[c*64+lane];
  float tvl=stv[lane];
  float gl=lng[j*64+lane], bl=lnb[j*64+lane];
  #pragma unroll
  for(int rr=0;rr<8;rr++){
    int r=wid*8+rr;
    const float4* rp=(const float4*)(sV + r*64);
    float vold = sV[r*64+lane];
    float m=tvl;
    #pragma unroll
    for(int c4=0;c4<16;c4++){
      float4 vv=rp[c4];
      m += vv.x*Tcol[c4*4]+vv.y*Tcol[c4*4+1]+vv.z*Tcol[c4*4+2]+vv.w*Tcol[c4*4+3];
    }
    m*=DXDY;
    float mean=wsum64(m)*(1.f/64.f);
    float d=m-mean;
    float var=wsum64(d*d)*(1.f/64.f);
    float y=d*(1.f/sqrtf(var+EPSC))*gl+bl+vold;
    vbase[r*64+lane]=y;
    sV[r*64+lane]=y;
  }
  __syncthreads();
  if(!cross){
    gram_tile8(sV, sV, wid, lane, Gdst+((size_t)(b*32+ch))*4096, gsdst+(b*32+ch)*64);
  } else if(ch<16){
    const float4* x4=(const float4*)(xy + ((size_t)b*2048+ch*64)*64);
    float4* sx4=(float4*)sG;
    #pragma unroll
    for(int e=0;e<2;e++) sx4[tid+e*512]=x4[tid+e*512];
    __syncthreads();
    gram_tile8(sV, sG, wid, lane, Gdst+((size_t)(b*16+ch))*4096, gsdst+(b*16+ch)*64);
  }
}

// ------ P = weight^T@Vu + weightf^T@Vf : lane owns jj (coalesced w loads); ------
// ------ V rows preloaded per-64n-chunk into lane VGPRs, broadcast by readlane ----
__global__ __launch_bounds__(512) void k_pw(const float* __restrict__ weight,
                                            const float* __restrict__ weightf,
                                            const float* __restrict__ Vin,
                                            float* __restrict__ PgA,
                                            float* __restrict__ PgB,
                                            float* __restrict__ wspart)
{
  int bid = blockIdx.x;                   // 256 = b(8) x jjc(2) x fs(4) x ns(4)
  int ns = bid&3, fs=(bid>>2)&3, jjc=(bid>>4)&1, b = bid>>5;
  int tid = threadIdx.x, lane = tid&63;
  int wid = __builtin_amdgcn_readfirstlane(tid>>6);
  int jj = jjc*512 + wid*64 + lane;
  const float* Vu = Vin + (size_t)b*131072 + fs*16;
  const float* Vf = Vu + 65536;
  float acc[16];
  #pragma unroll
  for(int k=0;k<16;k++) acc[k]=0.f;
  float cs = 0.f;
  for(int nc=0; nc<4; nc++){
    int nbase = ns*256 + nc*64;
    // lane preloads V row (nbase+lane): 16 f-values each for Vu/Vf
    float4 vu4[4], vf4[4];
    #pragma unroll
    for(int q=0;q<4;q++){
      vu4[q] = *(const float4*)&Vu[(size_t)(nbase+lane)*64 + q*4];
      vf4[q] = *(const float4*)&Vf[(size_t)(nbase+lane)*64 + q*4];
    }
    #pragma unroll 4
    for(int dn=0; dn<64; dn++){
      int n = nbase + dn;
      float w  = weight [n*1024 + jj];    // coalesced (256B/wave)
      float wf = weightf[n*1024 + jj];
      #pragma unroll
      for(int q=0;q<4;q++){
        #pragma unroll
        for(int e=0;e<4;e++){
          float vus = bcast(((const float*)&vu4[q])[e], dn);
          float vfs = bcast(((const float*)&vf4[q])[e], dn);
          acc[q*4+e] = fmaf(w,  vus, acc[q*4+e]);
          acc[q*4+e] = fmaf(wf, vfs, acc[q*4+e]);
        }
      }
      cs += w + wf;
    }
  }
  if(b==0 && fs==0) wspart[ns*1024 + jj] = cs;
  float* base = (ns<2) ? PgA : PgB;
  int nsl = ns&1;
  float* pp = base + ((size_t)(b*2+nsl)*1024 + jj)*64 + fs*16;
  float4* pp4 = (float4*)pp;
  #pragma unroll
  for(int m=0;m<4;m++)
    pp4[m] = make_float4(acc[m*4], acc[m*4+1], acc[m*4+2], acc[m*4+3]);
}

// ---------------- final (512 threads): redundant T3 build + out ----------------
__global__ __launch_bounds__(512) void k_final(
    const float* __restrict__ Gp2, const float* __restrict__ gsp2,
    const float* __restrict__ Mg, const float* __restrict__ ug,
    const float* __restrict__ vg, const float* __restrict__ cg,
    const float* __restrict__ PgA, const float* __restrict__ PgB,
    const float* __restrict__ wspart,
    float* __restrict__ out)
{
  __shared__ float sG[4096];
  __shared__ float sT[4096];
  __shared__ float stv[64];
  int blk = blockIdx.x, tid = threadIdx.x;       // grid 256
  int lane = tid&63;
  int wid = __builtin_amdgcn_readfirstlane(tid>>6);
  int b = blk>>5, rg = blk&31;
  {
    float4 a0={0,0,0,0},a1={0,0,0,0};
    const float4* gp4 = (const float4*)(Gp2 + (size_t)b*16*4096) + tid*2;
    for(int c=0;c<16;c++){
      const float4* p = gp4 + c*1024;
      float4 v0=p[0],v1=p[1];
      a0.x+=v0.x;a0.y+=v0.y;a0.z+=v0.z;a0.w+=v0.w;
      a1.x+=v1.x;a1.y+=v1.y;a1.z+=v1.z;a1.w+=v1.w;
    }
    float4* sg4=(float4*)sG + tid*2;
    sg4[0]=a0; sg4[1]=a1;
  }
  float gsl=0.f;
  for(int c=0;c<16;c++) gsl += gsp2[(b*16+c)*64+lane];
  __syncthreads();
  build_T8(sG, Mg+3*4096, ug+3*64, vg+3*64, cg[3], gsl, wid, lane, sT, stv);
  __syncthreads();
  float Tcol[64];
  #pragma unroll
  for(int c=0;c<64;c++) Tcol[c]=sT[c*64+lane];
  float t3l=stv[lane];
  #pragma unroll
  for(int rw=0;rw<4;rw++){
    int jj=rg*32+wid*4+rw;
    float p = PgA[((size_t)(b*2+0)*1024+jj)*64+lane]
            + PgA[((size_t)(b*2+1)*1024+jj)*64+lane]
            + PgB[((size_t)(b*2+0)*1024+jj)*64+lane]
            + PgB[((size_t)(b*2+1)*1024+jj)*64+lane];
    float wsm = wspart[jj] + wspart[1024+jj] + wspart[2048+jj] + wspart[3072+jj];
    float acc=wsm*t3l;
    #pragma unroll
    for(int c=0;c<64;c++) acc += __shfl(p,c)*Tcol[c];
    out[((size_t)(b*1024)+jj)*64+lane]=acc*(DXDY*DXDY);
  }
}

extern "C" void kernel_launch(void* const* d_in, const int* in_sizes, int n_in,
                              void* d_out, int out_size, void* d_ws, size_t ws_size,
                              hipStream_t stream)
{
  (void)in_sizes; (void)n_in; (void)out_size; (void)ws_size;
  const float* xy   = (const float*)d_in[0];
  const float* kW0  = (const float*)d_in[1];
  const float* kb0  = (const float*)d_in[2];
  const float* kW1  = (const float*)d_in[3];
  const float* kb1  = (const float*)d_in[4];
  const float* kW2  = (const float*)d_in[5];
  const float* kb2  = (const float*)d_in[6];
  const float* fW0  = (const float*)d_in[7];
  const float* fb0  = (const float*)d_in[8];
  const float* fW1  = (const float*)d_in[9];
  const float* fb1  = (const float*)d_in[10];
  const float* fW2  = (const float*)d_in[11];
  const float* fb2  = (const float*)d_in[12];
  const float* Wq   = (const float*)d_in[13];
  const float* bq   = (const float*)d_in[14];
  const float* Wk   = (const float*)d_in[15];
  const float* bk   = (const float*)d_in[16];
  const float* ln0g = (const float*)d_in[17];
  const float* ln0b = (const float*)d_in[18];
  const float* lng  = (const float*)d_in[19];
  const float* lnb  = (const float*)d_in[20];
  float* out = (float*)d_out;
  float* ws  = (float*)d_ws;

  float* lnp    = ws+OFF_LNP;
  float* Mg     = ws+OFF_M;
  float* ug     = ws+OFF_U;
  float* vg     = ws+OFF_V;
  float* cg     = ws+OFF_C;
  float* wspart = ws+OFF_WSPART;
  float* Vin    = ws+OFF_VIN;
  float* weight = ws+OFF_W;
  float* weightf= ws+OFF_WF;
  float* GPA    = ws+OFF_GPA;
  float* GSA    = ws+OFF_GSA;
  float* GPB    = ws+OFF_GPB;
  float* GSB    = ws+OFF_GSB;
  float* Pg     = ws+OFF_P;

  MlpW P = {kW0,kb0,kW1,kb1,kW2,kb2, fW0,fb0,fW1,fb1,fW2,fb2, weight, weightf};

  // prep partials land in GPB (dead until k_layer j=0 writes it; reduce runs in
  // k_ln0ag blocks 598-601 BEFORE k_layer(0) reads Mg)
  k_pre<<<192, 256, 0, stream>>>(xy, Wq, bq, Wk, bk, ws);
  k_ln0ag<<<602, 512, 0, stream>>>(xy, ln0g, ln0b, lnp, Vin, GPA, GSA, P, 0, ws);
  k_layer<<<256+341, 512, 0, stream>>>(Vin, xy, GPA, GSA, GPB, GSB,
                                       Mg, ug, vg, cg, lng, lnb, 0, 0, P, 684);
  k_layer<<<256+341, 512, 0, stream>>>(Vin, xy, GPB, GSB, GPA, GSA,
                                       Mg, ug, vg, cg, lng, lnb, 1, 0, P, 1366);
  k_layer<<<256, 512, 0, stream>>>(Vin, xy, GPA, GSA, GPB, GSB,
                                   Mg, ug, vg, cg, lng, lnb, 2, 1, P, 0);

  // GPA is dead after k_layer j=2 (it read GPA, wrote GPB) -> reuse for Pg ns 0/1
  k_pw<<<256, 512, 0, stream>>>(weight, weightf, Vin, GPA, Pg, wspart);
  k_final<<<256, 512, 0, stream>>>(GPB, GSB, Mg, ug, vg, cg, GPA, Pg, wspart, out);
}

// Round 14
// 221.040 us; speedup vs baseline: 1.0875x; 1.0875x over previous
//
#include <hip/hip_runtime.h>
#include <math.h>

#define BATCH 8
constexpr float DXC   = 2.0f/31.0f;
constexpr float DXDY  = DXC*DXC;
constexpr float SCALE = 0.125f;      // 1/sqrt(64), folded into M/u/v/c at reduce
constexpr float EPSC  = 1e-5f;
constexpr float SLOPEC= 0.01f;

// ---- workspace float offsets ----
#define OFF_LNP    0u         // 256
#define OFF_M      256u       // 16384
#define OFF_U      16640u     // 256
#define OFF_V      16896u     // 256
#define OFF_C      17152u     // 16
#define OFF_WSPART 17168u     // 4096 (4 ns-partials x 1024)
#define OFF_VIN    150288u    // 1048576
#define OFF_W      1198864u   // 1048576
#define OFF_WF     2247440u   // 1048576
#define OFF_GPA    3296016u   // 1048576  (gram partials A; reused as Pg ns0/1 at the end)
#define OFF_GSA    4344592u   // 16384
#define OFF_GPB    4360976u   // 1048576  (B; prep-partials live here pre-layer0)
#define OFF_GSB    5409552u   // 16384
#define OFF_P      5425936u   // 1048576  (Pg ns2/3)

// prep partial layout inside GPB: per (j,ch) stride 4352 = [4096 M][64 u][64 v][1 c][pad]
#define MP_STRIDE  4352

typedef short bf16x8 __attribute__((ext_vector_type(8)));
typedef float f32x4  __attribute__((ext_vector_type(4)));

struct MlpW {
  const float *kW0,*kb0,*kW1,*kb1,*kW2,*kb2;
  const float *fW0,*fb0,*fW1,*fb1,*fW2,*fb2;
  float *wo, *wfo;
};

__device__ __forceinline__ unsigned cvt2bf(float a, float b){
  unsigned r; asm("v_cvt_pk_bf16_f32 %0, %1, %2" : "=v"(r) : "v"(a), "v"(b)); return r;
}

__device__ __forceinline__ float lrelu(float x){ return fmaxf(x, SLOPEC*x); }

__device__ __forceinline__ float wsum64(float v){
  #pragma unroll
  for(int off=32; off; off>>=1) v += __shfl_xor(v, off);
  return v;
}

// -------- one edge-MLP unit (which,i) over all 1024 j, by 4 waves (swid 0..3) ------
__device__ __forceinline__ void mlp_unit(const MlpW P, int unit, int swid, int lane)
{
  int which = unit>>10, i = unit&1023;
  const float* W0 = which? P.fW0:P.kW0; const float* b0 = which? P.fb0:P.kb0;
  const float* W1 = which? P.fW1:P.kW1; const float* b1 = which? P.fb1:P.kb1;
  const float* W2 = which? P.fW2:P.kW2; const float* b2 = which? P.fb2:P.kb2;
  float* outp = which? P.wfo : P.wo;
  int grp = lane>>4, jl = lane&15;
  float xi = -1.f + DXC*(float)(i>>5), yi = -1.f + DXC*(float)(i&31);
  float a0c[8], wxc[8], wyc[8];
  #pragma unroll
  for(int t=0;t<8;t++){
    int c = grp*8+t;
    float4 w0 = *(const float4*)(W0 + c*4);
    a0c[t] = w0.x*xi + w0.y*yi + b0[c];
    wxc[t] = w0.z; wyc[t] = w0.w;
  }
  bf16x8 afr[4];
  #pragma unroll
  for(int ot=0;ot<4;ot++){
    const float* src = W1 + (ot*16+jl)*32 + grp*8;
    uint4 p;
    p.x=cvt2bf(src[0],src[1]); p.y=cvt2bf(src[2],src[3]);
    p.z=cvt2bf(src[4],src[5]); p.w=cvt2bf(src[6],src[7]);
    afr[ot] = __builtin_bit_cast(bf16x8, p);
  }
  float b1v[16], w2v[16];
  #pragma unroll
  for(int ot=0;ot<4;ot++){
    #pragma unroll
    for(int r=0;r<4;r++){
      int o = ot*16 + grp*4 + r;
      b1v[ot*4+r] = b1[o];
      w2v[ot*4+r] = W2[o];
    }
  }
  float b2s = b2[0];
  f32x4 zz = {0.f,0.f,0.f,0.f};
  int jbase = swid*256;
  for(int jt=0;jt<16;jt++){
    int j0 = jbase + jt*16;
    int j  = j0 + jl;
    float xj = -1.f + DXC*(float)(j>>5), yj = -1.f + DXC*(float)(j&31);
    float h[8];
    #pragma unroll
    for(int t=0;t<8;t++){
      float p = a0c[t] + wxc[t]*xj + wyc[t]*yj;
      h[t] = fmaxf(p, SLOPEC*p);
    }
    uint4 hb;
    hb.x=cvt2bf(h[0],h[1]); hb.y=cvt2bf(h[2],h[3]);
    hb.z=cvt2bf(h[4],h[5]); hb.w=cvt2bf(h[6],h[7]);
    bf16x8 bfr = __builtin_bit_cast(bf16x8, hb);
    f32x4 d0 = __builtin_amdgcn_mfma_f32_16x16x32_bf16(afr[0], bfr, zz, 0,0,0);
    f32x4 d1 = __builtin_amdgcn_mfma_f32_16x16x32_bf16(afr[1], bfr, zz, 0,0,0);
    f32x4 d2 = __builtin_amdgcn_mfma_f32_16x16x32_bf16(afr[2], bfr, zz, 0,0,0);
    f32x4 d3 = __builtin_amdgcn_mfma_f32_16x16x32_bf16(afr[3], bfr, zz, 0,0,0);
    float part = 0.f;
    #pragma unroll
    for(int r=0;r<4;r++){
      float s0 = d0[r]+b1v[r];    part = fmaf(w2v[r],    fmaxf(s0,SLOPEC*s0), part);
      float s1 = d1[r]+b1v[4+r];  part = fmaf(w2v[4+r],  fmaxf(s1,SLOPEC*s1), part);
      float s2 = d2[r]+b1v[8+r];  part = fmaf(w2v[8+r],  fmaxf(s2,SLOPEC*s2), part);
      float s3 = d3[r]+b1v[12+r]; part = fmaf(w2v[12+r], fmaxf(s3,SLOPEC*s3), part);
    }
    part += __shfl_xor(part, 16);
    part += __shfl_xor(part, 32);
    if(lane<16) outp[i*1024 + j0 + lane] = part + b2s;
  }
}

// ------- first launch: prep PARTIALS (64 blocks, 16 hk each) + LN0 partials -------
__global__ __launch_bounds__(256) void k_pre(
    const float* __restrict__ xy,
    const float* __restrict__ Wq, const float* __restrict__ bq,
    const float* __restrict__ Wk, const float* __restrict__ bk,
    float* __restrict__ ws)
{
  __shared__ float red[8];
  int blk = blockIdx.x, tid = threadIdx.x;
  int lane = tid&63;
  int wid = __builtin_amdgcn_readfirstlane(tid>>6);
  if(blk < 64){
    int j = blk>>4, ch = blk&15;
    float mac[16], uac[16];
    #pragma unroll
    for(int r=0;r<16;r++){ mac[r]=0.f; uac[r]=0.f; }
    float vac=0.f, cac=0.f;
    #pragma unroll 4
    for(int hk=ch*16; hk<ch*16+16; hk++){
      const float* wqrow = Wq + ((size_t)j*256+hk)*64;
      const float* wkrow = Wk + ((size_t)j*256+hk)*64;
      float wkl = wkrow[lane];
      float bkk = bk[j*256+hk], bqk = bq[j*256+hk];
      #pragma unroll
      for(int r=0;r<16;r++){ float wq=wqrow[wid*16+r]; mac[r]+=wq*wkl; uac[r]+=wq*bkk; }
      vac += bqk*wkl; cac += bqk*bkk;
    }
    float* mp = ws + OFF_GPB + (size_t)(j*16+ch)*MP_STRIDE;
    #pragma unroll
    for(int r=0;r<16;r++) mp[(wid*16+r)*64+lane] = mac[r];
    if(lane==0){
      #pragma unroll
      for(int r=0;r<16;r++) mp[4096 + wid*16+r] = uac[r];
    }
    if(wid==0) mp[4160+lane] = vac;
    if(tid==0) mp[4224] = cac;
  } else {
    int bb = blk-64;                             // 128 blocks
    int b = bb>>4, seg = bb&15;
    const float4* x4 = (const float4*)(xy + (size_t)b*131072 + seg*8192);
    float s=0.f, ss=0.f;
    #pragma unroll
    for(int k2=0;k2<8;k2++){
      float4 v = x4[tid + k2*256];
      s  += v.x+v.y+v.z+v.w;
      ss += v.x*v.x+v.y*v.y+v.z*v.z+v.w*v.w;
    }
    s = wsum64(s); ss = wsum64(ss);
    if(lane==0){ red[wid]=s; red[4+wid]=ss; }
    __syncthreads();
    if(tid==0){
      ws[OFF_LNP + (b*16+seg)*2  ] = red[0]+red[1]+red[2]+red[3];
      ws[OFF_LNP + (b*16+seg)*2+1] = red[4]+red[5]+red[6]+red[7];
    }
  }
}

// ---------------- Gram of 64x64 LDS tiles (8 waves: 8 cols each) ----------------
__device__ __forceinline__ void gram_tile8(const float* sA, const float* sB,
    int wid, int lane, float* __restrict__ gp, float* __restrict__ gsp)
{
  float acc[8];
  #pragma unroll
  for(int q=0;q<8;q++) acc[q]=0.f;
  float gsa=0.f;
  for(int m=0;m<64;m++){
    const float4* cp = (const float4*)(sA + m*64 + wid*8);
    float bml = sB[m*64+lane];
    float4 a0=cp[0],a1=cp[1];
    acc[0]+=a0.x*bml; acc[1]+=a0.y*bml; acc[2]+=a0.z*bml; acc[3]+=a0.w*bml;
    acc[4]+=a1.x*bml; acc[5]+=a1.y*bml; acc[6]+=a1.z*bml; acc[7]+=a1.w*bml;
    gsa += bml;
  }
  #pragma unroll
  for(int q=0;q<8;q++) gp[(wid*8+q)*64+lane]=acc[q];
  if(wid==0) gsp[lane]=gsa;
}

// ---------------- T build from LDS Gram (8 waves: 8 rows each) ----------------
__device__ __forceinline__ void build_T8(const float* __restrict__ sG,
    const float* __restrict__ Mj, const float* __restrict__ uj,
    const float* __restrict__ vj, float cj, float gsl,
    int wid, int lane, float* __restrict__ sT, float* __restrict__ stv)
{
  float gv[64];
  #pragma unroll
  for(int c=0;c<64;c++) gv[c]=sG[c*64+lane];
  float tacc = cj*gsl;
  #pragma unroll
  for(int c=0;c<64;c++) tacc += vj[c]*gv[c];
  #pragma unroll
  for(int rr=0;rr<8;rr++){
    int r = wid*8+rr;
    const float* mrow = Mj + r*64;                // wave-uniform -> s_load
    float acc = uj[r]*gsl;
    #pragma unroll
    for(int c=0;c<64;c++) acc += mrow[c]*gv[c];
    sT[r*64+lane]=acc;
  }
  if(wid==0) stv[lane]=tacc;
}

// ------- LN0 apply + Gram (512 thr) + MLP ride-along + prep-reduce blocks ---------
__global__ __launch_bounds__(512) void k_ln0ag(const float* __restrict__ xy,
    const float* __restrict__ g, const float* __restrict__ bb,
    const float* __restrict__ lnp,
    float* __restrict__ Vin, float* __restrict__ Gpart, float* __restrict__ gspart,
    MlpW P, int mlp_off, float* __restrict__ ws)
{
  __shared__ float sV[4096];
  int blk = blockIdx.x;
  int tid = threadIdx.x, lane = tid&63;
  int wid = __builtin_amdgcn_readfirstlane(tid>>6);
  if(blk >= 598){
    // reduce prep partials -> Mg/ug/vg/cg (4 blocks)
    int j = blk-598;
    const float* mp0 = ws + OFF_GPB + (size_t)(j*16)*MP_STRIDE;
    for(int e=tid; e<1024; e+=512){
      float4 s={0,0,0,0};
      for(int ch=0; ch<16; ch++){
        float4 v = *(const float4*)&mp0[(size_t)ch*MP_STRIDE + e*4];
        s.x+=v.x; s.y+=v.y; s.z+=v.z; s.w+=v.w;
      }
      s.x*=SCALE; s.y*=SCALE; s.z*=SCALE; s.w*=SCALE;
      *(float4*)&ws[OFF_M + j*4096 + e*4] = s;
    }
    if(tid<64){
      float su=0.f, sv=0.f;
      for(int ch=0; ch<16; ch++){
        su += mp0[(size_t)ch*MP_STRIDE + 4096 + tid];
        sv += mp0[(size_t)ch*MP_STRIDE + 4160 + tid];
      }
      ws[OFF_U + j*64+tid] = su*SCALE;
      ws[OFF_V + j*64+tid] = sv*SCALE;
    }
    if(tid==0){
      float sc=0.f;
      for(int ch=0; ch<16; ch++) sc += mp0[(size_t)ch*MP_STRIDE + 4224];
      ws[OFF_C + j] = sc*SCALE;
    }
    return;
  }
  if(blk >= 256){
    mlp_unit(P, mlp_off + (blk-256)*2 + (wid>>2), wid&3, lane);
    return;
  }
  int b = blk>>5, ch = blk&31;
  float s=0.f, ss=0.f;
  #pragma unroll
  for(int k2=0;k2<16;k2++){ s += lnp[(b*16+k2)*2]; ss += lnp[(b*16+k2)*2+1]; }
  float mean = s*(1.0f/131072.0f);
  float var  = ss*(1.0f/131072.0f) - mean*mean;
  float inv  = 1.0f/sqrtf(var+EPSC);
  const float4* x4 = (const float4*)(xy + ((size_t)b*2048 + ch*64)*64);
  const float4* g4 = (const float4*)(g  + (size_t)ch*4096);
  const float4* b4 = (const float4*)(bb + (size_t)ch*4096);
  float4* vo4 = (float4*)(Vin + ((size_t)b*2048 + ch*64)*64);
  float4* sv4 = (float4*)sV;
  #pragma unroll
  for(int e=0;e<2;e++){
    int idx = tid + e*512;
    float4 xv=x4[idx], gv=g4[idx], bv=b4[idx];
    float4 r;
    r.x=(xv.x-mean)*inv*gv.x+bv.x;
    r.y=(xv.y-mean)*inv*gv.y+bv.y;
    r.z=(xv.z-mean)*inv*gv.z+bv.z;
    r.w=(xv.w-mean)*inv*gv.w+bv.w;
    vo4[idx]=r; sv4[idx]=r;
  }
  __syncthreads();
  gram_tile8(sV, sV, wid, lane, Gpart+((size_t)(b*32+ch))*4096, gspart+(b*32+ch)*64);
}

// -------- layer (512 threads) + MLP ride-along ----------
__global__ __launch_bounds__(512) void k_layer(
    float* __restrict__ Vin, const float* __restrict__ xy,
    const float* __restrict__ Gsrc, const float* __restrict__ gssrc,
    float* __restrict__ Gdst, float* __restrict__ gsdst,
    const float* __restrict__ Mg, const float* __restrict__ ug,
    const float* __restrict__ vg, const float* __restrict__ cg,
    const float* __restrict__ lng, const float* __restrict__ lnb,
    int j, int cross, MlpW P, int mlp_off)
{
  __shared__ float sV[4096];
  __shared__ float sT[4096];
  __shared__ float sG[4096];
  __shared__ float stv[64];
  int blk = blockIdx.x, tid = threadIdx.x;
  int lane = tid&63;
  int wid = __builtin_amdgcn_readfirstlane(tid>>6);
  if(blk >= 256){
    mlp_unit(P, mlp_off + (blk-256)*2 + (wid>>2), wid&3, lane);
    return;
  }
  int b = blk>>5, ch = blk&31;
  float* vbase = Vin + ((size_t)b*2048 + ch*64)*64;
  {
    const float4* vb4=(const float4*)vbase;
    float4* sv4=(float4*)sV;
    #pragma unroll
    for(int e=0;e<2;e++) sv4[tid+e*512]=vb4[tid+e*512];
  }
  {
    float4 a0={0,0,0,0},a1={0,0,0,0};
    const float4* gp4 = (const float4*)(Gsrc + (size_t)b*32*4096) + tid*2;
    for(int c=0;c<32;c++){
      const float4* p = gp4 + c*1024;
      float4 v0=p[0],v1=p[1];
      a0.x+=v0.x;a0.y+=v0.y;a0.z+=v0.z;a0.w+=v0.w;
      a1.x+=v1.x;a1.y+=v1.y;a1.z+=v1.z;a1.w+=v1.w;
    }
    float4* sg4=(float4*)sG + tid*2;
    sg4[0]=a0; sg4[1]=a1;
  }
  float gsl=0.f;
  for(int c=0;c<32;c++) gsl += gssrc[(b*32+c)*64+lane];
  __syncthreads();
  build_T8(sG, Mg+j*4096, ug+j*64, vg+j*64, cg[j], gsl, wid, lane, sT, stv);
  __syncthreads();
  float Tcol[64];
  #pragma unroll
  for(int c=0;c<64;c++) Tcol[c]=sT[c*64+lane];
  float tvl=stv[lane];
  float gl=lng[j*64+lane], bl=lnb[j*64+lane];
  #pragma unroll
  for(int rr=0;rr<8;rr++){
    int r=wid*8+rr;
    const float4* rp=(const float4*)(sV + r*64);
    float vold = sV[r*64+lane];
    float m=tvl;
    #pragma unroll
    for(int c4=0;c4<16;c4++){
      float4 vv=rp[c4];
      m += vv.x*Tcol[c4*4]+vv.y*Tcol[c4*4+1]+vv.z*Tcol[c4*4+2]+vv.w*Tcol[c4*4+3];
    }
    m*=DXDY;
    float mean=wsum64(m)*(1.f/64.f);
    float d=m-mean;
    float var=wsum64(d*d)*(1.f/64.f);
    float y=d*(1.f/sqrtf(var+EPSC))*gl+bl+vold;
    vbase[r*64+lane]=y;
    sV[r*64+lane]=y;
  }
  __syncthreads();
  if(!cross){
    gram_tile8(sV, sV, wid, lane, Gdst+((size_t)(b*32+ch))*4096, gsdst+(b*32+ch)*64);
  } else if(ch<16){
    const float4* x4=(const float4*)(xy + ((size_t)b*2048+ch*64)*64);
    float4* sx4=(float4*)sG;
    #pragma unroll
    for(int e=0;e<2;e++) sx4[tid+e*512]=x4[tid+e*512];
    __syncthreads();
    gram_tile8(sV, sG, wid, lane, Gdst+((size_t)(b*16+ch))*4096, gsdst+(b*16+ch)*64);
  }
}

// ------ P = weight^T@Vu + weightf^T@Vf : lane owns jj (coalesced w loads); ------
// ------ V f-slice staged in LDS; inner loop = 2 vec loads + 8 uniform ds_read ----
// ------ + 32 FMA per n (low instr count AND low operand latency)            ----
__global__ __launch_bounds__(512) void k_pw(const float* __restrict__ weight,
                                            const float* __restrict__ weightf,
                                            const float* __restrict__ Vin,
                                            float* __restrict__ PgA,
                                            float* __restrict__ PgB,
                                            float* __restrict__ wspart)
{
  __shared__ float sVu[4096];             // [256 n][16 f] 16 KB
  __shared__ float sVf[4096];             // [256 n][16 f] 16 KB
  int bid = blockIdx.x;                   // 256 = b(8) x jjc(2) x fs(4) x ns(4)
  int ns = bid&3, fs=(bid>>2)&3, jjc=(bid>>4)&1, b = bid>>5;
  int tid = threadIdx.x, lane = tid&63;
  int wid = __builtin_amdgcn_readfirstlane(tid>>6);
  int jj = jjc*512 + wid*64 + lane;
  int nbase = ns*256;
  const float* Vu = Vin + (size_t)b*131072;
  const float* Vf = Vu + 65536;
  // stage V f-slice: thread t loads float4 (row dn = idx>>2, quad q = idx&3)
  {
    float4* su4 = (float4*)sVu;
    float4* sf4 = (float4*)sVf;
    #pragma unroll
    for(int pass=0; pass<2; pass++){
      int idx = tid + pass*512;
      int dn = idx>>2, q = idx&3;
      su4[idx] = *(const float4*)&Vu[(size_t)(nbase+dn)*64 + fs*16 + q*4];
      sf4[idx] = *(const float4*)&Vf[(size_t)(nbase+dn)*64 + fs*16 + q*4];
    }
  }
  __syncthreads();
  float acc[16];
  #pragma unroll
  for(int k=0;k<16;k++) acc[k]=0.f;
  float cs = 0.f;
  const float4* su4 = (const float4*)sVu;
  const float4* sf4 = (const float4*)sVf;
  #pragma unroll 4
  for(int dn=0; dn<256; dn++){
    int n = nbase + dn;
    float w  = weight [n*1024 + jj];      // coalesced vector load (256B/wave)
    float wf = weightf[n*1024 + jj];
    #pragma unroll
    for(int q=0;q<4;q++){
      float4 vu = su4[dn*4+q];            // wave-uniform ds_read_b128 (broadcast)
      float4 vf = sf4[dn*4+q];
      acc[q*4+0] = fmaf(w, vu.x, fmaf(wf, vf.x, acc[q*4+0]));
      acc[q*4+1] = fmaf(w, vu.y, fmaf(wf, vf.y, acc[q*4+1]));
      acc[q*4+2] = fmaf(w, vu.z, fmaf(wf, vf.z, acc[q*4+2]));
      acc[q*4+3] = fmaf(w, vu.w, fmaf(wf, vf.w, acc[q*4+3]));
    }
    cs += w + wf;
  }
  if(b==0 && fs==0) wspart[ns*1024 + jj] = cs;
  float* base = (ns<2) ? PgA : PgB;
  int nsl = ns&1;
  float* pp = base + ((size_t)(b*2+nsl)*1024 + jj)*64 + fs*16;
  float4* pp4 = (float4*)pp;
  #pragma unroll
  for(int m=0;m<4;m++)
    pp4[m] = make_float4(acc[m*4], acc[m*4+1], acc[m*4+2], acc[m*4+3]);
}

// ---------------- final (512 threads): redundant T3 build + out ----------------
__global__ __launch_bounds__(512) void k_final(
    const float* __restrict__ Gp2, const float* __restrict__ gsp2,
    const float* __restrict__ Mg, const float* __restrict__ ug,
    const float* __restrict__ vg, const float* __restrict__ cg,
    const float* __restrict__ PgA, const float* __restrict__ PgB,
    const float* __restrict__ wspart,
    float* __restrict__ out)
{
  __shared__ float sG[4096];
  __shared__ float sT[4096];
  __shared__ float stv[64];
  int blk = blockIdx.x, tid = threadIdx.x;       // grid 256
  int lane = tid&63;
  int wid = __builtin_amdgcn_readfirstlane(tid>>6);
  int b = blk>>5, rg = blk&31;
  {
    float4 a0={0,0,0,0},a1={0,0,0,0};
    const float4* gp4 = (const float4*)(Gp2 + (size_t)b*16*4096) + tid*2;
    for(int c=0;c<16;c++){
      const float4* p = gp4 + c*1024;
      float4 v0=p[0],v1=p[1];
      a0.x+=v0.x;a0.y+=v0.y;a0.z+=v0.z;a0.w+=v0.w;
      a1.x+=v1.x;a1.y+=v1.y;a1.z+=v1.z;a1.w+=v1.w;
    }
    float4* sg4=(float4*)sG + tid*2;
    sg4[0]=a0; sg4[1]=a1;
  }
  float gsl=0.f;
  for(int c=0;c<16;c++) gsl += gsp2[(b*16+c)*64+lane];
  __syncthreads();
  build_T8(sG, Mg+3*4096, ug+3*64, vg+3*64, cg[3], gsl, wid, lane, sT, stv);
  __syncthreads();
  float Tcol[64];
  #pragma unroll
  for(int c=0;c<64;c++) Tcol[c]=sT[c*64+lane];
  float t3l=stv[lane];
  #pragma unroll
  for(int rw=0;rw<4;rw++){
    int jj=rg*32+wid*4+rw;
    float p = PgA[((size_t)(b*2+0)*1024+jj)*64+lane]
            + PgA[((size_t)(b*2+1)*1024+jj)*64+lane]
            + PgB[((size_t)(b*2+0)*1024+jj)*64+lane]
            + PgB[((size_t)(b*2+1)*1024+jj)*64+lane];
    float wsm = wspart[jj] + wspart[1024+jj] + wspart[2048+jj] + wspart[3072+jj];
    float acc=wsm*t3l;
    #pragma unroll
    for(int c=0;c<64;c++) acc += __shfl(p,c)*Tcol[c];
    out[((size_t)(b*1024)+jj)*64+lane]=acc*(DXDY*DXDY);
  }
}

extern "C" void kernel_launch(void* const* d_in, const int* in_sizes, int n_in,
                              void* d_out, int out_size, void* d_ws, size_t ws_size,
                              hipStream_t stream)
{
  (void)in_sizes; (void)n_in; (void)out_size; (void)ws_size;
  const float* xy   = (const float*)d_in[0];
  const float* kW0  = (const float*)d_in[1];
  const float* kb0  = (const float*)d_in[2];
  const float* kW1  = (const float*)d_in[3];
  const float* kb1  = (const float*)d_in[4];
  const float* kW2  = (const float*)d_in[5];
  const float* kb2  = (const float*)d_in[6];
  const float* fW0  = (const float*)d_in[7];
  const float* fb0  = (const float*)d_in[8];
  const float* fW1  = (const float*)d_in[9];
  const float* fb1  = (const float*)d_in[10];
  const float* fW2  = (const float*)d_in[11];
  const float* fb2  = (const float*)d_in[12];
  const float* Wq   = (const float*)d_in[13];
  const float* bq   = (const float*)d_in[14];
  const float* Wk   = (const float*)d_in[15];
  const float* bk   = (const float*)d_in[16];
  const float* ln0g = (const float*)d_in[17];
  const float* ln0b = (const float*)d_in[18];
  const float* lng  = (const float*)d_in[19];
  const float* lnb  = (const float*)d_in[20];
  float* out = (float*)d_out;
  float* ws  = (float*)d_ws;

  float* lnp    = ws+OFF_LNP;
  float* Mg     = ws+OFF_M;
  float* ug     = ws+OFF_U;
  float* vg     = ws+OFF_V;
  float* cg     = ws+OFF_C;
  float* wspart = ws+OFF_WSPART;
  float* Vin    = ws+OFF_VIN;
  float* weight = ws+OFF_W;
  float* weightf= ws+OFF_WF;
  float* GPA    = ws+OFF_GPA;
  float* GSA    = ws+OFF_GSA;
  float* GPB    = ws+OFF_GPB;
  float* GSB    = ws+OFF_GSB;
  float* Pg     = ws+OFF_P;

  MlpW P = {kW0,kb0,kW1,kb1,kW2,kb2, fW0,fb0,fW1,fb1,fW2,fb2, weight, weightf};

  // prep partials land in GPB (dead until k_layer j=0 writes it; reduce runs in
  // k_ln0ag blocks 598-601 BEFORE k_layer(0) reads Mg)
  k_pre<<<192, 256, 0, stream>>>(xy, Wq, bq, Wk, bk, ws);
  k_ln0ag<<<602, 512, 0, stream>>>(xy, ln0g, ln0b, lnp, Vin, GPA, GSA, P, 0, ws);
  k_layer<<<256+341, 512, 0, stream>>>(Vin, xy, GPA, GSA, GPB, GSB,
                                       Mg, ug, vg, cg, lng, lnb, 0, 0, P, 684);
  k_layer<<<256+341, 512, 0, stream>>>(Vin, xy, GPB, GSB, GPA, GSA,
                                       Mg, ug, vg, cg, lng, lnb, 1, 0, P, 1366);
  k_layer<<<256, 512, 0, stream>>>(Vin, xy, GPA, GSA, GPB, GSB,
                                   Mg, ug, vg, cg, lng, lnb, 2, 1, P, 0);

  // GPA is dead after k_layer j=2 (it read GPA, wrote GPB) -> reuse for Pg ns 0/1
  k_pw<<<256, 512, 0, stream>>>(weight, weightf, Vin, GPA, Pg, wspart);
  k_final<<<256, 512, 0, stream>>>(GPB, GSB, Mg, ug, vg, cg, GPA, Pg, wspart, out);
}

// Round 15
// 193.565 us; speedup vs baseline: 1.2419x; 1.1419x over previous
//
#include <hip/hip_runtime.h>
#include <math.h>

#define BATCH 8
constexpr float DXC   = 2.0f/31.0f;
constexpr float DXDY  = DXC*DXC;
constexpr float SCALE = 0.125f;      // 1/sqrt(64), folded into M/u/v/c at reduce
constexpr float EPSC  = 1e-5f;
constexpr float SLOPEC= 0.01f;

// ---- workspace float offsets ----
#define OFF_LNP    0u         // 256
#define OFF_M      256u       // 16384
#define OFF_U      16640u     // 256
#define OFF_V      16896u     // 256
#define OFF_C      17152u     // 16
#define OFF_WSPART 17168u     // 4096 (4 ns-partials x 1024)
#define OFF_VIN    150288u    // 1048576
#define OFF_W      1198864u   // 1048576
#define OFF_WF     2247440u   // 1048576
#define OFF_GPA    3296016u   // 1048576  (gram partials A; reused as Pg ns0/1 at the end)
#define OFF_GSA    4344592u   // 16384
#define OFF_GPB    4360976u   // 1048576  (B; prep-partials live here pre-layer0)
#define OFF_GSB    5409552u   // 16384
#define OFF_P      5425936u   // 1048576  (Pg ns2/3)

// prep partial layout inside GPB: per (j,ch) stride 4352 = [4096 M][64 u][64 v][1 c][pad]
#define MP_STRIDE  4352

typedef short bf16x8 __attribute__((ext_vector_type(8)));
typedef float f32x4  __attribute__((ext_vector_type(4)));

struct MlpW {
  const float *kW0,*kb0,*kW1,*kb1,*kW2,*kb2;
  const float *fW0,*fb0,*fW1,*fb1,*fW2,*fb2;
  float *wo, *wfo;
};

__device__ __forceinline__ unsigned cvt2bf(float a, float b){
  unsigned r; asm("v_cvt_pk_bf16_f32 %0, %1, %2" : "=v"(r) : "v"(a), "v"(b)); return r;
}

__device__ __forceinline__ float lrelu(float x){ return fmaxf(x, SLOPEC*x); }

__device__ __forceinline__ float wsum64(float v){
  #pragma unroll
  for(int off=32; off; off>>=1) v += __shfl_xor(v, off);
  return v;
}

// -------- one edge-MLP unit (which,i) over all 1024 j, by 4 waves (swid 0..3) ------
__device__ __forceinline__ void mlp_unit(const MlpW P, int unit, int swid, int lane)
{
  int which = unit>>10, i = unit&1023;
  const float* W0 = which? P.fW0:P.kW0; const float* b0 = which? P.fb0:P.kb0;
  const float* W1 = which? P.fW1:P.kW1; const float* b1 = which? P.fb1:P.kb1;
  const float* W2 = which? P.fW2:P.kW2; const float* b2 = which? P.fb2:P.kb2;
  float* outp = which? P.wfo : P.wo;
  int grp = lane>>4, jl = lane&15;
  float xi = -1.f + DXC*(float)(i>>5), yi = -1.f + DXC*(float)(i&31);
  float a0c[8], wxc[8], wyc[8];
  #pragma unroll
  for(int t=0;t<8;t++){
    int c = grp*8+t;
    float4 w0 = *(const float4*)(W0 + c*4);
    a0c[t] = w0.x*xi + w0.y*yi + b0[c];
    wxc[t] = w0.z; wyc[t] = w0.w;
  }
  bf16x8 afr[4];
  #pragma unroll
  for(int ot=0;ot<4;ot++){
    const float* src = W1 + (ot*16+jl)*32 + grp*8;
    uint4 p;
    p.x=cvt2bf(src[0],src[1]); p.y=cvt2bf(src[2],src[3]);
    p.z=cvt2bf(src[4],src[5]); p.w=cvt2bf(src[6],src[7]);
    afr[ot] = __builtin_bit_cast(bf16x8, p);
  }
  float b1v[16], w2v[16];
  #pragma unroll
  for(int ot=0;ot<4;ot++){
    #pragma unroll
    for(int r=0;r<4;r++){
      int o = ot*16 + grp*4 + r;
      b1v[ot*4+r] = b1[o];
      w2v[ot*4+r] = W2[o];
    }
  }
  float b2s = b2[0];
  f32x4 zz = {0.f,0.f,0.f,0.f};
  int jbase = swid*256;
  for(int jt=0;jt<16;jt++){
    int j0 = jbase + jt*16;
    int j  = j0 + jl;
    float xj = -1.f + DXC*(float)(j>>5), yj = -1.f + DXC*(float)(j&31);
    float h[8];
    #pragma unroll
    for(int t=0;t<8;t++){
      float p = a0c[t] + wxc[t]*xj + wyc[t]*yj;
      h[t] = fmaxf(p, SLOPEC*p);
    }
    uint4 hb;
    hb.x=cvt2bf(h[0],h[1]); hb.y=cvt2bf(h[2],h[3]);
    hb.z=cvt2bf(h[4],h[5]); hb.w=cvt2bf(h[6],h[7]);
    bf16x8 bfr = __builtin_bit_cast(bf16x8, hb);
    f32x4 d0 = __builtin_amdgcn_mfma_f32_16x16x32_bf16(afr[0], bfr, zz, 0,0,0);
    f32x4 d1 = __builtin_amdgcn_mfma_f32_16x16x32_bf16(afr[1], bfr, zz, 0,0,0);
    f32x4 d2 = __builtin_amdgcn_mfma_f32_16x16x32_bf16(afr[2], bfr, zz, 0,0,0);
    f32x4 d3 = __builtin_amdgcn_mfma_f32_16x16x32_bf16(afr[3], bfr, zz, 0,0,0);
    float part = 0.f;
    #pragma unroll
    for(int r=0;r<4;r++){
      float s0 = d0[r]+b1v[r];    part = fmaf(w2v[r],    fmaxf(s0,SLOPEC*s0), part);
      float s1 = d1[r]+b1v[4+r];  part = fmaf(w2v[4+r],  fmaxf(s1,SLOPEC*s1), part);
      float s2 = d2[r]+b1v[8+r];  part = fmaf(w2v[8+r],  fmaxf(s2,SLOPEC*s2), part);
      float s3 = d3[r]+b1v[12+r]; part = fmaf(w2v[12+r], fmaxf(s3,SLOPEC*s3), part);
    }
    part += __shfl_xor(part, 16);
    part += __shfl_xor(part, 32);
    if(lane<16) outp[i*1024 + j0 + lane] = part + b2s;
  }
}

// ------- first launch: prep PARTIALS (64 blocks, 16 hk each) + LN0 partials -------
__global__ __launch_bounds__(256) void k_pre(
    const float* __restrict__ xy,
    const float* __restrict__ Wq, const float* __restrict__ bq,
    const float* __restrict__ Wk, const float* __restrict__ bk,
    float* __restrict__ ws)
{
  __shared__ float red[8];
  int blk = blockIdx.x, tid = threadIdx.x;
  int lane = tid&63;
  int wid = __builtin_amdgcn_readfirstlane(tid>>6);
  if(blk < 64){
    int j = blk>>4, ch = blk&15;
    float mac[16], uac[16];
    #pragma unroll
    for(int r=0;r<16;r++){ mac[r]=0.f; uac[r]=0.f; }
    float vac=0.f, cac=0.f;
    #pragma unroll 4
    for(int hk=ch*16; hk<ch*16+16; hk++){
      const float* wqrow = Wq + ((size_t)j*256+hk)*64;
      const float* wkrow = Wk + ((size_t)j*256+hk)*64;
      float wkl = wkrow[lane];
      float bkk = bk[j*256+hk], bqk = bq[j*256+hk];
      #pragma unroll
      for(int r=0;r<16;r++){ float wq=wqrow[wid*16+r]; mac[r]+=wq*wkl; uac[r]+=wq*bkk; }
      vac += bqk*wkl; cac += bqk*bkk;
    }
    float* mp = ws + OFF_GPB + (size_t)(j*16+ch)*MP_STRIDE;
    #pragma unroll
    for(int r=0;r<16;r++) mp[(wid*16+r)*64+lane] = mac[r];
    if(lane==0){
      #pragma unroll
      for(int r=0;r<16;r++) mp[4096 + wid*16+r] = uac[r];
    }
    if(wid==0) mp[4160+lane] = vac;
    if(tid==0) mp[4224] = cac;
  } else {
    int bb = blk-64;                             // 128 blocks
    int b = bb>>4, seg = bb&15;
    const float4* x4 = (const float4*)(xy + (size_t)b*131072 + seg*8192);
    float s=0.f, ss=0.f;
    #pragma unroll
    for(int k2=0;k2<8;k2++){
      float4 v = x4[tid + k2*256];
      s  += v.x+v.y+v.z+v.w;
      ss += v.x*v.x+v.y*v.y+v.z*v.z+v.w*v.w;
    }
    s = wsum64(s); ss = wsum64(ss);
    if(lane==0){ red[wid]=s; red[4+wid]=ss; }
    __syncthreads();
    if(tid==0){
      ws[OFF_LNP + (b*16+seg)*2  ] = red[0]+red[1]+red[2]+red[3];
      ws[OFF_LNP + (b*16+seg)*2+1] = red[4]+red[5]+red[6]+red[7];
    }
  }
}

// ---------------- Gram of 64x64 LDS tiles (8 waves: 8 cols each) ----------------
__device__ __forceinline__ void gram_tile8(const float* sA, const float* sB,
    int wid, int lane, float* __restrict__ gp, float* __restrict__ gsp)
{
  float acc[8];
  #pragma unroll
  for(int q=0;q<8;q++) acc[q]=0.f;
  float gsa=0.f;
  for(int m=0;m<64;m++){
    const float4* cp = (const float4*)(sA + m*64 + wid*8);
    float bml = sB[m*64+lane];
    float4 a0=cp[0],a1=cp[1];
    acc[0]+=a0.x*bml; acc[1]+=a0.y*bml; acc[2]+=a0.z*bml; acc[3]+=a0.w*bml;
    acc[4]+=a1.x*bml; acc[5]+=a1.y*bml; acc[6]+=a1.z*bml; acc[7]+=a1.w*bml;
    gsa += bml;
  }
  #pragma unroll
  for(int q=0;q<8;q++) gp[(wid*8+q)*64+lane]=acc[q];
  if(wid==0) gsp[lane]=gsa;
}

// ---------------- T build from LDS Gram (8 waves: 8 rows each) ----------------
__device__ __forceinline__ void build_T8(const float* __restrict__ sG,
    const float* __restrict__ Mj, const float* __restrict__ uj,
    const float* __restrict__ vj, float cj, float gsl,
    int wid, int lane, float* __restrict__ sT, float* __restrict__ stv)
{
  float gv[64];
  #pragma unroll
  for(int c=0;c<64;c++) gv[c]=sG[c*64+lane];
  float tacc = cj*gsl;
  #pragma unroll
  for(int c=0;c<64;c++) tacc += vj[c]*gv[c];
  #pragma unroll
  for(int rr=0;rr<8;rr++){
    int r = wid*8+rr;
    const float* mrow = Mj + r*64;                // wave-uniform -> s_load
    float acc = uj[r]*gsl;
    #pragma unroll
    for(int c=0;c<64;c++) acc += mrow[c]*gv[c];
    sT[r*64+lane]=acc;
  }
  if(wid==0) stv[lane]=tacc;
}

// ------- LN0 apply + Gram (512 thr) + MLP ride-along + prep-reduce blocks ---------
__global__ __launch_bounds__(512) void k_ln0ag(const float* __restrict__ xy,
    const float* __restrict__ g, const float* __restrict__ bb,
    const float* __restrict__ lnp,
    float* __restrict__ Vin, float* __restrict__ Gpart, float* __restrict__ gspart,
    MlpW P, int mlp_off, float* __restrict__ ws)
{
  __shared__ float sV[4096];
  int blk = blockIdx.x;
  int tid = threadIdx.x, lane = tid&63;
  int wid = __builtin_amdgcn_readfirstlane(tid>>6);
  if(blk >= 598){
    // reduce prep partials -> Mg/ug/vg/cg (4 blocks)
    int j = blk-598;
    const float* mp0 = ws + OFF_GPB + (size_t)(j*16)*MP_STRIDE;
    for(int e=tid; e<1024; e+=512){
      float4 s={0,0,0,0};
      for(int ch=0; ch<16; ch++){
        float4 v = *(const float4*)&mp0[(size_t)ch*MP_STRIDE + e*4];
        s.x+=v.x; s.y+=v.y; s.z+=v.z; s.w+=v.w;
      }
      s.x*=SCALE; s.y*=SCALE; s.z*=SCALE; s.w*=SCALE;
      *(float4*)&ws[OFF_M + j*4096 + e*4] = s;
    }
    if(tid<64){
      float su=0.f, sv=0.f;
      for(int ch=0; ch<16; ch++){
        su += mp0[(size_t)ch*MP_STRIDE + 4096 + tid];
        sv += mp0[(size_t)ch*MP_STRIDE + 4160 + tid];
      }
      ws[OFF_U + j*64+tid] = su*SCALE;
      ws[OFF_V + j*64+tid] = sv*SCALE;
    }
    if(tid==0){
      float sc=0.f;
      for(int ch=0; ch<16; ch++) sc += mp0[(size_t)ch*MP_STRIDE + 4224];
      ws[OFF_C + j] = sc*SCALE;
    }
    return;
  }
  if(blk >= 256){
    mlp_unit(P, mlp_off + (blk-256)*2 + (wid>>2), wid&3, lane);
    return;
  }
  int b = blk>>5, ch = blk&31;
  float s=0.f, ss=0.f;
  #pragma unroll
  for(int k2=0;k2<16;k2++){ s += lnp[(b*16+k2)*2]; ss += lnp[(b*16+k2)*2+1]; }
  float mean = s*(1.0f/131072.0f);
  float var  = ss*(1.0f/131072.0f) - mean*mean;
  float inv  = 1.0f/sqrtf(var+EPSC);
  const float4* x4 = (const float4*)(xy + ((size_t)b*2048 + ch*64)*64);
  const float4* g4 = (const float4*)(g  + (size_t)ch*4096);
  const float4* b4 = (const float4*)(bb + (size_t)ch*4096);
  float4* vo4 = (float4*)(Vin + ((size_t)b*2048 + ch*64)*64);
  float4* sv4 = (float4*)sV;
  #pragma unroll
  for(int e=0;e<2;e++){
    int idx = tid + e*512;
    float4 xv=x4[idx], gv=g4[idx], bv=b4[idx];
    float4 r;
    r.x=(xv.x-mean)*inv*gv.x+bv.x;
    r.y=(xv.y-mean)*inv*gv.y+bv.y;
    r.z=(xv.z-mean)*inv*gv.z+bv.z;
    r.w=(xv.w-mean)*inv*gv.w+bv.w;
    vo4[idx]=r; sv4[idx]=r;
  }
  __syncthreads();
  gram_tile8(sV, sV, wid, lane, Gpart+((size_t)(b*32+ch))*4096, gspart+(b*32+ch)*64);
}

// -------- layer (512 threads) + MLP ride-along ----------
__global__ __launch_bounds__(512) void k_layer(
    float* __restrict__ Vin, const float* __restrict__ xy,
    const float* __restrict__ Gsrc, const float* __restrict__ gssrc,
    float* __restrict__ Gdst, float* __restrict__ gsdst,
    const float* __restrict__ Mg, const float* __restrict__ ug,
    const float* __restrict__ vg, const float* __restrict__ cg,
    const float* __restrict__ lng, const float* __restrict__ lnb,
    int j, int cross, MlpW P, int mlp_off)
{
  __shared__ float sV[4096];
  __shared__ float sT[4096];
  __shared__ float sG[4096];
  __shared__ float stv[64];
  int blk = blockIdx.x, tid = threadIdx.x;
  int lane = tid&63;
  int wid = __builtin_amdgcn_readfirstlane(tid>>6);
  if(blk >= 256){
    mlp_unit(P, mlp_off + (blk-256)*2 + (wid>>2), wid&3, lane);
    return;
  }
  int b = blk>>5, ch = blk&31;
  float* vbase = Vin + ((size_t)b*2048 + ch*64)*64;
  {
    const float4* vb4=(const float4*)vbase;
    float4* sv4=(float4*)sV;
    #pragma unroll
    for(int e=0;e<2;e++) sv4[tid+e*512]=vb4[tid+e*512];
  }
  {
    float4 a0={0,0,0,0},a1={0,0,0,0};
    const float4* gp4 = (const float4*)(Gsrc + (size_t)b*32*4096) + tid*2;
    for(int c=0;c<32;c++){
      const float4* p = gp4 + c*1024;
      float4 v0=p[0],v1=p[1];
      a0.x+=v0.x;a0.y+=v0.y;a0.z+=v0.z;a0.w+=v0.w;
      a1.x+=v1.x;a1.y+=v1.y;a1.z+=v1.z;a1.w+=v1.w;
    }
    float4* sg4=(float4*)sG + tid*2;
    sg4[0]=a0; sg4[1]=a1;
  }
  float gsl=0.f;
  for(int c=0;c<32;c++) gsl += gssrc[(b*32+c)*64+lane];
  __syncthreads();
  build_T8(sG, Mg+j*4096, ug+j*64, vg+j*64, cg[j], gsl, wid, lane, sT, stv);
  __syncthreads();
  float Tcol[64];
  #pragma unroll
  for(int c=0;c<64;c++) Tcol[c]=sT[c*64+lane];
  float tvl=stv[lane];
  float gl=lng[j*64+lane], bl=lnb[j*64+lane];
  #pragma unroll
  for(int rr=0;rr<8;rr++){
    int r=wid*8+rr;
    const float4* rp=(const float4*)(sV + r*64);
    float vold = sV[r*64+lane];
    float m=tvl;
    #pragma unroll
    for(int c4=0;c4<16;c4++){
      float4 vv=rp[c4];
      m += vv.x*Tcol[c4*4]+vv.y*Tcol[c4*4+1]+vv.z*Tcol[c4*4+2]+vv.w*Tcol[c4*4+3];
    }
    m*=DXDY;
    float mean=wsum64(m)*(1.f/64.f);
    float d=m-mean;
    float var=wsum64(d*d)*(1.f/64.f);
    float y=d*(1.f/sqrtf(var+EPSC))*gl+bl+vold;
    vbase[r*64+lane]=y;
    sV[r*64+lane]=y;
  }
  __syncthreads();
  if(!cross){
    gram_tile8(sV, sV, wid, lane, Gdst+((size_t)(b*32+ch))*4096, gsdst+(b*32+ch)*64);
  } else if(ch<16){
    const float4* x4=(const float4*)(xy + ((size_t)b*2048+ch*64)*64);
    float4* sx4=(float4*)sG;
    #pragma unroll
    for(int e=0;e<2;e++) sx4[tid+e*512]=x4[tid+e*512];
    __syncthreads();
    gram_tile8(sV, sG, wid, lane, Gdst+((size_t)(b*16+ch))*4096, gsdst+(b*16+ch)*64);
  }
}

// ------ P = weight^T@Vu + weightf^T@Vf : lane owns jj (coalesced w loads); ------
// ------ V 8-f slice via wave-uniform s_load with EXPLICIT n+1 PREFETCH;    ------
// ------ fs=8 split -> 512 blocks, zero LDS -> 2 blocks/CU, 16 waves/CU     ------
__global__ __launch_bounds__(512) void k_pw(const float* __restrict__ weight,
                                            const float* __restrict__ weightf,
                                            const float* __restrict__ Vin,
                                            float* __restrict__ PgA,
                                            float* __restrict__ PgB,
                                            float* __restrict__ wspart)
{
  int bid = blockIdx.x;                   // 512 = b(8) x jjc(2) x fs(8) x ns(4)
  int ns = bid&3, fs=(bid>>2)&7, jjc=(bid>>5)&1, b = bid>>6;
  int tid = threadIdx.x;
  int jj = jjc*512 + tid;
  const float* Vu = Vin + (size_t)b*131072 + fs*8;
  const float* Vf = Vu + 65536;
  float acc[8];
  #pragma unroll
  for(int k=0;k<8;k++) acc[k]=0.f;
  float cs = 0.f;
  int n0 = ns*256;
  float vu_c[8], vf_c[8];
  #pragma unroll
  for(int k=0;k<8;k++){ vu_c[k]=Vu[(size_t)n0*64+k]; vf_c[k]=Vf[(size_t)n0*64+k]; }
  #pragma unroll 2
  for(int dn=0; dn<256; dn++){
    int n = n0 + dn;
    float w  = weight [n*1024 + jj];      // coalesced vector load
    float wf = weightf[n*1024 + jj];
    // prefetch next V row into SGPRs (dn==255 over-reads into OFF_W region: harmless,
    // within d_ws, values unused)
    float vu_n[8], vf_n[8];
    #pragma unroll
    for(int k=0;k<8;k++){ vu_n[k]=Vu[(size_t)(n+1)*64+k]; vf_n[k]=Vf[(size_t)(n+1)*64+k]; }
    #pragma unroll
    for(int k=0;k<8;k++)
      acc[k] = fmaf(w, vu_c[k], fmaf(wf, vf_c[k], acc[k]));
    cs += w + wf;
    #pragma unroll
    for(int k=0;k<8;k++){ vu_c[k]=vu_n[k]; vf_c[k]=vf_n[k]; }
  }
  if(b==0 && fs==0) wspart[ns*1024 + jj] = cs;
  float* base = (ns<2) ? PgA : PgB;
  int nsl = ns&1;
  float* pp = base + ((size_t)(b*2+nsl)*1024 + jj)*64 + fs*8;
  float4* pp4 = (float4*)pp;
  pp4[0] = make_float4(acc[0], acc[1], acc[2], acc[3]);
  pp4[1] = make_float4(acc[4], acc[5], acc[6], acc[7]);
}

// ---------------- final (512 threads): redundant T3 build + out ----------------
__global__ __launch_bounds__(512) void k_final(
    const float* __restrict__ Gp2, const float* __restrict__ gsp2,
    const float* __restrict__ Mg, const float* __restrict__ ug,
    const float* __restrict__ vg, const float* __restrict__ cg,
    const float* __restrict__ PgA, const float* __restrict__ PgB,
    const float* __restrict__ wspart,
    float* __restrict__ out)
{
  __shared__ float sG[4096];
  __shared__ float sT[4096];
  __shared__ float stv[64];
  int blk = blockIdx.x, tid = threadIdx.x;       // grid 256
  int lane = tid&63;
  int wid = __builtin_amdgcn_readfirstlane(tid>>6);
  int b = blk>>5, rg = blk&31;
  {
    float4 a0={0,0,0,0},a1={0,0,0,0};
    const float4* gp4 = (const float4*)(Gp2 + (size_t)b*16*4096) + tid*2;
    for(int c=0;c<16;c++){
      const float4* p = gp4 + c*1024;
      float4 v0=p[0],v1=p[1];
      a0.x+=v0.x;a0.y+=v0.y;a0.z+=v0.z;a0.w+=v0.w;
      a1.x+=v1.x;a1.y+=v1.y;a1.z+=v1.z;a1.w+=v1.w;
    }
    float4* sg4=(float4*)sG + tid*2;
    sg4[0]=a0; sg4[1]=a1;
  }
  float gsl=0.f;
  for(int c=0;c<16;c++) gsl += gsp2[(b*16+c)*64+lane];
  __syncthreads();
  build_T8(sG, Mg+3*4096, ug+3*64, vg+3*64, cg[3], gsl, wid, lane, sT, stv);
  __syncthreads();
  float Tcol[64];
  #pragma unroll
  for(int c=0;c<64;c++) Tcol[c]=sT[c*64+lane];
  float t3l=stv[lane];
  #pragma unroll
  for(int rw=0;rw<4;rw++){
    int jj=rg*32+wid*4+rw;
    float p = PgA[((size_t)(b*2+0)*1024+jj)*64+lane]
            + PgA[((size_t)(b*2+1)*1024+jj)*64+lane]
            + PgB[((size_t)(b*2+0)*1024+jj)*64+lane]
            + PgB[((size_t)(b*2+1)*1024+jj)*64+lane];
    float wsm = wspart[jj] + wspart[1024+jj] + wspart[2048+jj] + wspart[3072+jj];
    float acc=wsm*t3l;
    #pragma unroll
    for(int c=0;c<64;c++) acc += __shfl(p,c)*Tcol[c];
    out[((size_t)(b*1024)+jj)*64+lane]=acc*(DXDY*DXDY);
  }
}

extern "C" void kernel_launch(void* const* d_in, const int* in_sizes, int n_in,
                              void* d_out, int out_size, void* d_ws, size_t ws_size,
                              hipStream_t stream)
{
  (void)in_sizes; (void)n_in; (void)out_size; (void)ws_size;
  const float* xy   = (const float*)d_in[0];
  const float* kW0  = (const float*)d_in[1];
  const float* kb0  = (const float*)d_in[2];
  const float* kW1  = (const float*)d_in[3];
  const float* kb1  = (const float*)d_in[4];
  const float* kW2  = (const float*)d_in[5];
  const float* kb2  = (const float*)d_in[6];
  const float* fW0  = (const float*)d_in[7];
  const float* fb0  = (const float*)d_in[8];
  const float* fW1  = (const float*)d_in[9];
  const float* fb1  = (const float*)d_in[10];
  const float* fW2  = (const float*)d_in[11];
  const float* fb2  = (const float*)d_in[12];
  const float* Wq   = (const float*)d_in[13];
  const float* bq   = (const float*)d_in[14];
  const float* Wk   = (const float*)d_in[15];
  const float* bk   = (const float*)d_in[16];
  const float* ln0g = (const float*)d_in[17];
  const float* ln0b = (const float*)d_in[18];
  const float* lng  = (const float*)d_in[19];
  const float* lnb  = (const float*)d_in[20];
  float* out = (float*)d_out;
  float* ws  = (float*)d_ws;

  float* lnp    = ws+OFF_LNP;
  float* Mg     = ws+OFF_M;
  float* ug     = ws+OFF_U;
  float* vg     = ws+OFF_V;
  float* cg     = ws+OFF_C;
  float* wspart = ws+OFF_WSPART;
  float* Vin    = ws+OFF_VIN;
  float* weight = ws+OFF_W;
  float* weightf= ws+OFF_WF;
  float* GPA    = ws+OFF_GPA;
  float* GSA    = ws+OFF_GSA;
  float* GPB    = ws+OFF_GPB;
  float* GSB    = ws+OFF_GSB;
  float* Pg     = ws+OFF_P;

  MlpW P = {kW0,kb0,kW1,kb1,kW2,kb2, fW0,fb0,fW1,fb1,fW2,fb2, weight, weightf};

  // prep partials land in GPB (dead until k_layer j=0 writes it; reduce runs in
  // k_ln0ag blocks 598-601 BEFORE k_layer(0) reads Mg)
  k_pre<<<192, 256, 0, stream>>>(xy, Wq, bq, Wk, bk, ws);
  k_ln0ag<<<602, 512, 0, stream>>>(xy, ln0g, ln0b, lnp, Vin, GPA, GSA, P, 0, ws);
  k_layer<<<256+341, 512, 0, stream>>>(Vin, xy, GPA, GSA, GPB, GSB,
                                       Mg, ug, vg, cg, lng, lnb, 0, 0, P, 684);
  k_layer<<<256+341, 512, 0, stream>>>(Vin, xy, GPB, GSB, GPA, GSA,
                                       Mg, ug, vg, cg, lng, lnb, 1, 0, P, 1366);
  k_layer<<<256, 512, 0, stream>>>(Vin, xy, GPA, GSA, GPB, GSB,
                                   Mg, ug, vg, cg, lng, lnb, 2, 1, P, 0);

  // GPA is dead after k_layer j=2 (it read GPA, wrote GPB) -> reuse for Pg ns 0/1
  k_pw<<<512, 512, 0, stream>>>(weight, weightf, Vin, GPA, Pg, wspart);
  k_final<<<256, 512, 0, stream>>>(GPB, GSB, Mg, ug, vg, cg, GPA, Pg, wspart, out);
}

// Round 16
// 168.079 us; speedup vs baseline: 1.4302x; 1.1516x over previous
//
#include <hip/hip_runtime.h>
#include <math.h>

#define BATCH 8
constexpr float DXC   = 2.0f/31.0f;
constexpr float DXDY  = DXC*DXC;
constexpr float SCALE = 0.125f;      // 1/sqrt(64), folded into M/u/v/c at reduce
constexpr float EPSC  = 1e-5f;
constexpr float SLOPEC= 0.01f;

// ---- workspace float offsets ----
#define OFF_LNP    0u         // 256
#define OFF_M      256u       // 16384
#define OFF_U      16640u     // 256
#define OFF_V      16896u     // 256
#define OFF_C      17152u     // 16
#define OFF_WSP2   17168u     // 32768 (2 mat x 16 nt x 1024 jj colsum partials)
#define OFF_VIN    150288u    // 1048576
#define OFF_W      1198864u   // 1048576
#define OFF_WF     2247440u   // 1048576
#define OFF_GPA    3296016u   // 1048576 (gram partials A; P ns0 at the end)
#define OFF_GSA    4344592u   // 16384
#define OFF_GPB    4360976u   // 1048576 (lower: cross-gram; upper: P ns1)
#define OFF_GSB    5409552u   // 16384
#define OFF_P      5425936u   // 1048576 floats = 4MB: Wt + Wft as bf16
// prep partial layout inside GPB (pre-layer0): per (j,ch) stride 4352
#define MP_STRIDE  4352

typedef short bf16x8 __attribute__((ext_vector_type(8)));
typedef float f32x4  __attribute__((ext_vector_type(4)));

struct MlpW {
  const float *kW0,*kb0,*kW1,*kb1,*kW2,*kb2;
  const float *fW0,*fb0,*fW1,*fb1,*fW2,*fb2;
  float *wo, *wfo;
};

__device__ __forceinline__ unsigned cvt2bf(float a, float b){
  unsigned r; asm("v_cvt_pk_bf16_f32 %0, %1, %2" : "=v"(r) : "v"(a), "v"(b)); return r;
}

__device__ __forceinline__ float lrelu(float x){ return fmaxf(x, SLOPEC*x); }

__device__ __forceinline__ float wsum64(float v){
  #pragma unroll
  for(int off=32; off; off>>=1) v += __shfl_xor(v, off);
  return v;
}

// -------- one edge-MLP unit (which,i) over all 1024 j, by 4 waves (swid 0..3) ------
__device__ __forceinline__ void mlp_unit(const MlpW P, int unit, int swid, int lane)
{
  int which = unit>>10, i = unit&1023;
  const float* W0 = which? P.fW0:P.kW0; const float* b0 = which? P.fb0:P.kb0;
  const float* W1 = which? P.fW1:P.kW1; const float* b1 = which? P.fb1:P.kb1;
  const float* W2 = which? P.fW2:P.kW2; const float* b2 = which? P.fb2:P.kb2;
  float* outp = which? P.wfo : P.wo;
  int grp = lane>>4, jl = lane&15;
  float xi = -1.f + DXC*(float)(i>>5), yi = -1.f + DXC*(float)(i&31);
  float a0c[8], wxc[8], wyc[8];
  #pragma unroll
  for(int t=0;t<8;t++){
    int c = grp*8+t;
    float4 w0 = *(const float4*)(W0 + c*4);
    a0c[t] = w0.x*xi + w0.y*yi + b0[c];
    wxc[t] = w0.z; wyc[t] = w0.w;
  }
  bf16x8 afr[4];
  #pragma unroll
  for(int ot=0;ot<4;ot++){
    const float* src = W1 + (ot*16+jl)*32 + grp*8;
    uint4 p;
    p.x=cvt2bf(src[0],src[1]); p.y=cvt2bf(src[2],src[3]);
    p.z=cvt2bf(src[4],src[5]); p.w=cvt2bf(src[6],src[7]);
    afr[ot] = __builtin_bit_cast(bf16x8, p);
  }
  float b1v[16], w2v[16];
  #pragma unroll
  for(int ot=0;ot<4;ot++){
    #pragma unroll
    for(int r=0;r<4;r++){
      int o = ot*16 + grp*4 + r;
      b1v[ot*4+r] = b1[o];
      w2v[ot*4+r] = W2[o];
    }
  }
  float b2s = b2[0];
  f32x4 zz = {0.f,0.f,0.f,0.f};
  int jbase = swid*256;
  for(int jt=0;jt<16;jt++){
    int j0 = jbase + jt*16;
    int j  = j0 + jl;
    float xj = -1.f + DXC*(float)(j>>5), yj = -1.f + DXC*(float)(j&31);
    float h[8];
    #pragma unroll
    for(int t=0;t<8;t++){
      float p = a0c[t] + wxc[t]*xj + wyc[t]*yj;
      h[t] = fmaxf(p, SLOPEC*p);
    }
    uint4 hb;
    hb.x=cvt2bf(h[0],h[1]); hb.y=cvt2bf(h[2],h[3]);
    hb.z=cvt2bf(h[4],h[5]); hb.w=cvt2bf(h[6],h[7]);
    bf16x8 bfr = __builtin_bit_cast(bf16x8, hb);
    f32x4 d0 = __builtin_amdgcn_mfma_f32_16x16x32_bf16(afr[0], bfr, zz, 0,0,0);
    f32x4 d1 = __builtin_amdgcn_mfma_f32_16x16x32_bf16(afr[1], bfr, zz, 0,0,0);
    f32x4 d2 = __builtin_amdgcn_mfma_f32_16x16x32_bf16(afr[2], bfr, zz, 0,0,0);
    f32x4 d3 = __builtin_amdgcn_mfma_f32_16x16x32_bf16(afr[3], bfr, zz, 0,0,0);
    float part = 0.f;
    #pragma unroll
    for(int r=0;r<4;r++){
      float s0 = d0[r]+b1v[r];    part = fmaf(w2v[r],    fmaxf(s0,SLOPEC*s0), part);
      float s1 = d1[r]+b1v[4+r];  part = fmaf(w2v[4+r],  fmaxf(s1,SLOPEC*s1), part);
      float s2 = d2[r]+b1v[8+r];  part = fmaf(w2v[8+r],  fmaxf(s2,SLOPEC*s2), part);
      float s3 = d3[r]+b1v[12+r]; part = fmaf(w2v[12+r], fmaxf(s3,SLOPEC*s3), part);
    }
    part += __shfl_xor(part, 16);
    part += __shfl_xor(part, 32);
    if(lane<16) outp[i*1024 + j0 + lane] = part + b2s;
  }
}

// -------- transpose+bf16 one 64x64 tile of weight -> Wt[jj][n], + colsum partial ----
__device__ __forceinline__ void transpose_unit(const float* __restrict__ src,
    unsigned short* __restrict__ dst, float* __restrict__ wsp2row,
    int n0, int jj0, unsigned short* S, int utid)
{
  int np = utid&31, jq = utid>>5;             // np 0..31 (n-pairs), jq 0..7 (8 jj each)
  const float* r0 = src + (size_t)(n0 + 2*np)*1024 + jj0 + jq*8;
  const float* r1 = r0 + 1024;
  float av[8], bv[8];
  *(float4*)&av[0] = *(const float4*)r0;  *(float4*)&av[4] = *(const float4*)(r0+4);
  *(float4*)&bv[0] = *(const float4*)r1;  *(float4*)&bv[4] = *(const float4*)(r1+4);
  unsigned* S32 = (unsigned*)S;
  #pragma unroll
  for(int e=0;e<8;e++)
    S32[((jq*8+e)*72 + 2*np)>>1] = cvt2bf(av[e], bv[e]);   // lo=n even, hi=n odd
  __syncthreads();
  int jl = utid>>2, seg = utid&3;
  uint4 s0 = *(uint4*)&S[jl*72 + seg*16];
  uint4 s1 = *(uint4*)&S[jl*72 + seg*16 + 8];
  unsigned short* orow = dst + (size_t)(jj0+jl)*1024 + n0 + seg*16;
  *(uint4*)orow = s0;
  *(uint4*)(orow+8) = s1;
  if(utid < 64){
    const unsigned* Sr = (const unsigned*)&S[utid*72];
    float acc = 0.f;
    #pragma unroll
    for(int h=0;h<32;h++){
      unsigned v = Sr[h];
      acc += __builtin_bit_cast(float, v<<16);
      acc += __builtin_bit_cast(float, v & 0xffff0000u);
    }
    wsp2row[jj0 + utid] = acc;
  }
}

// ------- first launch: prep PARTIALS (64 blocks, 16 hk each) + LN0 partials -------
__global__ __launch_bounds__(256) void k_pre(
    const float* __restrict__ xy,
    const float* __restrict__ Wq, const float* __restrict__ bq,
    const float* __restrict__ Wk, const float* __restrict__ bk,
    float* __restrict__ ws)
{
  __shared__ float red[8];
  int blk = blockIdx.x, tid = threadIdx.x;
  int lane = tid&63;
  int wid = __builtin_amdgcn_readfirstlane(tid>>6);
  if(blk < 64){
    int j = blk>>4, ch = blk&15;
    float mac[16], uac[16];
    #pragma unroll
    for(int r=0;r<16;r++){ mac[r]=0.f; uac[r]=0.f; }
    float vac=0.f, cac=0.f;
    #pragma unroll 4
    for(int hk=ch*16; hk<ch*16+16; hk++){
      const float* wqrow = Wq + ((size_t)j*256+hk)*64;
      const float* wkrow = Wk + ((size_t)j*256+hk)*64;
      float wkl = wkrow[lane];
      float bkk = bk[j*256+hk], bqk = bq[j*256+hk];
      #pragma unroll
      for(int r=0;r<16;r++){ float wq=wqrow[wid*16+r]; mac[r]+=wq*wkl; uac[r]+=wq*bkk; }
      vac += bqk*wkl; cac += bqk*bkk;
    }
    float* mp = ws + OFF_GPB + (size_t)(j*16+ch)*MP_STRIDE;
    #pragma unroll
    for(int r=0;r<16;r++) mp[(wid*16+r)*64+lane] = mac[r];
    if(lane==0){
      #pragma unroll
      for(int r=0;r<16;r++) mp[4096 + wid*16+r] = uac[r];
    }
    if(wid==0) mp[4160+lane] = vac;
    if(tid==0) mp[4224] = cac;
  } else {
    int bb = blk-64;                             // 128 blocks
    int b = bb>>4, seg = bb&15;
    const float4* x4 = (const float4*)(xy + (size_t)b*131072 + seg*8192);
    float s=0.f, ss=0.f;
    #pragma unroll
    for(int k2=0;k2<8;k2++){
      float4 v = x4[tid + k2*256];
      s  += v.x+v.y+v.z+v.w;
      ss += v.x*v.x+v.y*v.y+v.z*v.z+v.w*v.w;
    }
    s = wsum64(s); ss = wsum64(ss);
    if(lane==0){ red[wid]=s; red[4+wid]=ss; }
    __syncthreads();
    if(tid==0){
      ws[OFF_LNP + (b*16+seg)*2  ] = red[0]+red[1]+red[2]+red[3];
      ws[OFF_LNP + (b*16+seg)*2+1] = red[4]+red[5]+red[6]+red[7];
    }
  }
}

// ---------------- Gram of 64x64 LDS tiles (8 waves: 8 cols each) ----------------
__device__ __forceinline__ void gram_tile8(const float* sA, const float* sB,
    int wid, int lane, float* __restrict__ gp, float* __restrict__ gsp)
{
  float acc[8];
  #pragma unroll
  for(int q=0;q<8;q++) acc[q]=0.f;
  float gsa=0.f;
  for(int m=0;m<64;m++){
    const float4* cp = (const float4*)(sA + m*64 + wid*8);
    float bml = sB[m*64+lane];
    float4 a0=cp[0],a1=cp[1];
    acc[0]+=a0.x*bml; acc[1]+=a0.y*bml; acc[2]+=a0.z*bml; acc[3]+=a0.w*bml;
    acc[4]+=a1.x*bml; acc[5]+=a1.y*bml; acc[6]+=a1.z*bml; acc[7]+=a1.w*bml;
    gsa += bml;
  }
  #pragma unroll
  for(int q=0;q<8;q++) gp[(wid*8+q)*64+lane]=acc[q];
  if(wid==0) gsp[lane]=gsa;
}

// ---------------- T build from LDS Gram (8 waves: 8 rows each) ----------------
__device__ __forceinline__ void build_T8(const float* __restrict__ sG,
    const float* __restrict__ Mj, const float* __restrict__ uj,
    const float* __restrict__ vj, float cj, float gsl,
    int wid, int lane, float* __restrict__ sT, float* __restrict__ stv)
{
  float gv[64];
  #pragma unroll
  for(int c=0;c<64;c++) gv[c]=sG[c*64+lane];
  float tacc = cj*gsl;
  #pragma unroll
  for(int c=0;c<64;c++) tacc += vj[c]*gv[c];
  #pragma unroll
  for(int rr=0;rr<8;rr++){
    int r = wid*8+rr;
    const float* mrow = Mj + r*64;                // wave-uniform -> s_load
    float acc = uj[r]*gsl;
    #pragma unroll
    for(int c=0;c<64;c++) acc += mrow[c]*gv[c];
    sT[r*64+lane]=acc;
  }
  if(wid==0) stv[lane]=tacc;
}

// ------- LN0 apply + Gram (512 thr) + MLP ride-along + prep-reduce blocks ---------
__global__ __launch_bounds__(512) void k_ln0ag(const float* __restrict__ xy,
    const float* __restrict__ g, const float* __restrict__ bb,
    const float* __restrict__ lnp,
    float* __restrict__ Vin, float* __restrict__ Gpart, float* __restrict__ gspart,
    MlpW P, int mlp_off, float* __restrict__ ws)
{
  __shared__ float sV[4096];
  int blk = blockIdx.x;
  int tid = threadIdx.x, lane = tid&63;
  int wid = __builtin_amdgcn_readfirstlane(tid>>6);
  if(blk >= 598){
    int j = blk-598;
    const float* mp0 = ws + OFF_GPB + (size_t)(j*16)*MP_STRIDE;
    for(int e=tid; e<1024; e+=512){
      float4 s={0,0,0,0};
      for(int ch=0; ch<16; ch++){
        float4 v = *(const float4*)&mp0[(size_t)ch*MP_STRIDE + e*4];
        s.x+=v.x; s.y+=v.y; s.z+=v.z; s.w+=v.w;
      }
      s.x*=SCALE; s.y*=SCALE; s.z*=SCALE; s.w*=SCALE;
      *(float4*)&ws[OFF_M + j*4096 + e*4] = s;
    }
    if(tid<64){
      float su=0.f, sv=0.f;
      for(int ch=0; ch<16; ch++){
        su += mp0[(size_t)ch*MP_STRIDE + 4096 + tid];
        sv += mp0[(size_t)ch*MP_STRIDE + 4160 + tid];
      }
      ws[OFF_U + j*64+tid] = su*SCALE;
      ws[OFF_V + j*64+tid] = sv*SCALE;
    }
    if(tid==0){
      float sc=0.f;
      for(int ch=0; ch<16; ch++) sc += mp0[(size_t)ch*MP_STRIDE + 4224];
      ws[OFF_C + j] = sc*SCALE;
    }
    return;
  }
  if(blk >= 256){
    mlp_unit(P, mlp_off + (blk-256)*2 + (wid>>2), wid&3, lane);
    return;
  }
  int b = blk>>5, ch = blk&31;
  float s=0.f, ss=0.f;
  #pragma unroll
  for(int k2=0;k2<16;k2++){ s += lnp[(b*16+k2)*2]; ss += lnp[(b*16+k2)*2+1]; }
  float mean = s*(1.0f/131072.0f);
  float var  = ss*(1.0f/131072.0f) - mean*mean;
  float inv  = 1.0f/sqrtf(var+EPSC);
  const float4* x4 = (const float4*)(xy + ((size_t)b*2048 + ch*64)*64);
  const float4* g4 = (const float4*)(g  + (size_t)ch*4096);
  const float4* b4 = (const float4*)(bb + (size_t)ch*4096);
  float4* vo4 = (float4*)(Vin + ((size_t)b*2048 + ch*64)*64);
  float4* sv4 = (float4*)sV;
  #pragma unroll
  for(int e=0;e<2;e++){
    int idx = tid + e*512;
    float4 xv=x4[idx], gv=g4[idx], bv=b4[idx];
    float4 r;
    r.x=(xv.x-mean)*inv*gv.x+bv.x;
    r.y=(xv.y-mean)*inv*gv.y+bv.y;
    r.z=(xv.z-mean)*inv*gv.z+bv.z;
    r.w=(xv.w-mean)*inv*gv.w+bv.w;
    vo4[idx]=r; sv4[idx]=r;
  }
  __syncthreads();
  gram_tile8(sV, sV, wid, lane, Gpart+((size_t)(b*32+ch))*4096, gspart+(b*32+ch)*64);
}

// -------- layer (512 threads) + ride-along: MLP (emode 0) or transpose (emode 1) ---
__global__ __launch_bounds__(512) void k_layer(
    float* __restrict__ Vin, const float* __restrict__ xy,
    const float* __restrict__ Gsrc, const float* __restrict__ gssrc,
    float* __restrict__ Gdst, float* __restrict__ gsdst,
    const float* __restrict__ Mg, const float* __restrict__ ug,
    const float* __restrict__ vg, const float* __restrict__ cg,
    const float* __restrict__ lng, const float* __restrict__ lnb,
    int j, int cross, MlpW P, int mlp_off,
    unsigned short* __restrict__ wtg, unsigned short* __restrict__ wftg,
    float* __restrict__ wsp2, int emode)
{
  __shared__ __align__(16) float sV[4096];
  __shared__ __align__(16) float sT[4096];
  __shared__ __align__(16) float sG[4096];
  __shared__ float stv[64];
  int blk = blockIdx.x, tid = threadIdx.x;
  int lane = tid&63;
  int wid = __builtin_amdgcn_readfirstlane(tid>>6);
  if(blk >= 256){
    if(emode == 0){
      mlp_unit(P, mlp_off + (blk-256)*2 + (wid>>2), wid&3, lane);
    } else {
      int half = tid>>8;                          // waves 0-3 / 4-7
      int unit = (blk-256)*2 + half;              // 0..511
      int utid = tid & 255;
      int mat = unit>>8, tile = unit&255;
      int nt = tile>>4, jt = tile&15;
      unsigned short* S = (unsigned short*)(half? sT : sV);
      transpose_unit(mat? P.wfo : P.wo, mat? wftg : wtg,
                     wsp2 + (mat*16 + nt)*1024, nt*64, jt*64, S, utid);
    }
    return;
  }
  int b = blk>>5, ch = blk&31;
  float* vbase = Vin + ((size_t)b*2048 + ch*64)*64;
  {
    const float4* vb4=(const float4*)vbase;
    float4* sv4=(float4*)sV;
    #pragma unroll
    for(int e=0;e<2;e++) sv4[tid+e*512]=vb4[tid+e*512];
  }
  {
    float4 a0={0,0,0,0},a1={0,0,0,0};
    const float4* gp4 = (const float4*)(Gsrc + (size_t)b*32*4096) + tid*2;
    for(int c=0;c<32;c++){
      const float4* p = gp4 + c*1024;
      float4 v0=p[0],v1=p[1];
      a0.x+=v0.x;a0.y+=v0.y;a0.z+=v0.z;a0.w+=v0.w;
      a1.x+=v1.x;a1.y+=v1.y;a1.z+=v1.z;a1.w+=v1.w;
    }
    float4* sg4=(float4*)sG + tid*2;
    sg4[0]=a0; sg4[1]=a1;
  }
  float gsl=0.f;
  for(int c=0;c<32;c++) gsl += gssrc[(b*32+c)*64+lane];
  __syncthreads();
  build_T8(sG, Mg+j*4096, ug+j*64, vg+j*64, cg[j], gsl, wid, lane, sT, stv);
  __syncthreads();
  float Tcol[64];
  #pragma unroll
  for(int c=0;c<64;c++) Tcol[c]=sT[c*64+lane];
  float tvl=stv[lane];
  float gl=lng[j*64+lane], bl=lnb[j*64+lane];
  #pragma unroll
  for(int rr=0;rr<8;rr++){
    int r=wid*8+rr;
    const float4* rp=(const float4*)(sV + r*64);
    float vold = sV[r*64+lane];
    float m=tvl;
    #pragma unroll
    for(int c4=0;c4<16;c4++){
      float4 vv=rp[c4];
      m += vv.x*Tcol[c4*4]+vv.y*Tcol[c4*4+1]+vv.z*Tcol[c4*4+2]+vv.w*Tcol[c4*4+3];
    }
    m*=DXDY;
    float mean=wsum64(m)*(1.f/64.f);
    float d=m-mean;
    float var=wsum64(d*d)*(1.f/64.f);
    float y=d*(1.f/sqrtf(var+EPSC))*gl+bl+vold;
    vbase[r*64+lane]=y;
    sV[r*64+lane]=y;
  }
  __syncthreads();
  if(!cross){
    gram_tile8(sV, sV, wid, lane, Gdst+((size_t)(b*32+ch))*4096, gsdst+(b*32+ch)*64);
  } else if(ch<16){
    const float4* x4=(const float4*)(xy + ((size_t)b*2048+ch*64)*64);
    float4* sx4=(float4*)sG;
    #pragma unroll
    for(int e=0;e<2;e++) sx4[tid+e*512]=x4[tid+e*512];
    __syncthreads();
    gram_tile8(sV, sG, wid, lane, Gdst+((size_t)(b*16+ch))*4096, gsdst+(b*16+ch)*64);
  }
}

// ------ P = Wt^T-GEMM via MFMA: D[16jj x 64f] per wave, K=512 per block (ns=2) -----
__global__ __launch_bounds__(256) void k_pw(
    const unsigned short* __restrict__ WtG, const unsigned short* __restrict__ WftG,
    const float* __restrict__ Vin,
    float* __restrict__ P0, float* __restrict__ P1)
{
  __shared__ __align__(16) unsigned short sVu[64*72];   // [f][n-padded] bf16
  __shared__ __align__(16) unsigned short sVf[64*72];
  int bid = blockIdx.x;                 // 256 = b(8) x jjc(16) x ns(2)
  int ns = bid&1, jjc = (bid>>1)&15, b = bid>>5;
  int tid = threadIdx.x, lane = tid&63;
  int wid = __builtin_amdgcn_readfirstlane(tid>>6);
  int jl = lane&15, grp = lane>>4;
  int jjw = jjc*64 + wid*16;
  const float* Vu = Vin + (size_t)b*131072;
  const float* Vf = Vu + 65536;
  f32x4 acc[4] = {{0,0,0,0},{0,0,0,0},{0,0,0,0},{0,0,0,0}};
  int np = tid&31, fq = tid>>5;         // staging: 32 n-pairs x 8 f-groups
  unsigned* Su = (unsigned*)sVu;
  unsigned* Sf = (unsigned*)sVf;
  for(int step=0; step<8; step++){
    int nb = ns*512 + step*64;
    {
      const float* u0 = Vu + (size_t)(nb + 2*np)*64 + fq*8;
      const float* f0 = Vf + (size_t)(nb + 2*np)*64 + fq*8;
      float ua[8], ub[8], fa[8], fb[8];
      *(float4*)&ua[0] = *(const float4*)u0;      *(float4*)&ua[4] = *(const float4*)(u0+4);
      *(float4*)&ub[0] = *(const float4*)(u0+64); *(float4*)&ub[4] = *(const float4*)(u0+68);
      *(float4*)&fa[0] = *(const float4*)f0;      *(float4*)&fa[4] = *(const float4*)(f0+4);
      *(float4*)&fb[0] = *(const float4*)(f0+64); *(float4*)&fb[4] = *(const float4*)(f0+68);
      #pragma unroll
      for(int e=0;e<8;e++){
        Su[((fq*8+e)*72 + 2*np)>>1] = cvt2bf(ua[e], ub[e]);
        Sf[((fq*8+e)*72 + 2*np)>>1] = cvt2bf(fa[e], fb[e]);
      }
    }
    __syncthreads();
    #pragma unroll
    for(int ks=0; ks<2; ks++){
      int kk = ks*32;
      bf16x8 aw  = *(const bf16x8*)&WtG [(size_t)(jjw+jl)*1024 + nb + kk + grp*8];
      bf16x8 awf = *(const bf16x8*)&WftG[(size_t)(jjw+jl)*1024 + nb + kk + grp*8];
      #pragma unroll
      for(int ft=0; ft<4; ft++){
        bf16x8 bu = *(const bf16x8*)&sVu[(ft*16+jl)*72 + kk + grp*8];
        bf16x8 bv = *(const bf16x8*)&sVf[(ft*16+jl)*72 + kk + grp*8];
        acc[ft] = __builtin_amdgcn_mfma_f32_16x16x32_bf16(aw,  bu, acc[ft], 0,0,0);
        acc[ft] = __builtin_amdgcn_mfma_f32_16x16x32_bf16(awf, bv, acc[ft], 0,0,0);
      }
    }
    __syncthreads();
  }
  float* Pd = (ns? P1 : P0) + ((size_t)b*1024 + jjw)*64;
  #pragma unroll
  for(int ft=0; ft<4; ft++){
    #pragma unroll
    for(int r=0;r<4;r++){
      int row = grp*4 + r;
      Pd[(size_t)row*64 + ft*16 + jl] = acc[ft][r];
    }
  }
}

// ---------------- final (512 threads): redundant T3 build + out ----------------
__global__ __launch_bounds__(512) void k_final(
    const float* __restrict__ Gp2, const float* __restrict__ gsp2,
    const float* __restrict__ Mg, const float* __restrict__ ug,
    const float* __restrict__ vg, const float* __restrict__ cg,
    const float* __restrict__ P0, const float* __restrict__ P1,
    const float* __restrict__ wsp2,
    float* __restrict__ out)
{
  __shared__ float sG[4096];
  __shared__ float sT[4096];
  __shared__ float stv[64];
  int blk = blockIdx.x, tid = threadIdx.x;       // grid 256
  int lane = tid&63;
  int wid = __builtin_amdgcn_readfirstlane(tid>>6);
  int b = blk>>5, rg = blk&31;
  {
    float4 a0={0,0,0,0},a1={0,0,0,0};
    const float4* gp4 = (const float4*)(Gp2 + (size_t)b*16*4096) + tid*2;
    for(int c=0;c<16;c++){
      const float4* p = gp4 + c*1024;
      float4 v0=p[0],v1=p[1];
      a0.x+=v0.x;a0.y+=v0.y;a0.z+=v0.z;a0.w+=v0.w;
      a1.x+=v1.x;a1.y+=v1.y;a1.z+=v1.z;a1.w+=v1.w;
    }
    float4* sg4=(float4*)sG + tid*2;
    sg4[0]=a0; sg4[1]=a1;
  }
  float gsl=0.f;
  for(int c=0;c<16;c++) gsl += gsp2[(b*16+c)*64+lane];
  __syncthreads();
  build_T8(sG, Mg+3*4096, ug+3*64, vg+3*64, cg[3], gsl, wid, lane, sT, stv);
  __syncthreads();
  float Tcol[64];
  #pragma unroll
  for(int c=0;c<64;c++) Tcol[c]=sT[c*64+lane];
  float t3l=stv[lane];
  #pragma unroll
  for(int rw=0;rw<4;rw++){
    int jj=rg*32+wid*4+rw;
    float p = P0[((size_t)b*1024+jj)*64+lane]
            + P1[((size_t)b*1024+jj)*64+lane];
    float wsm = 0.f;
    #pragma unroll
    for(int c=0;c<32;c++) wsm += wsp2[c*1024+jj];
    float acc=wsm*t3l;
    #pragma unroll
    for(int c=0;c<64;c++) acc += __shfl(p,c)*Tcol[c];
    out[((size_t)(b*1024)+jj)*64+lane]=acc*(DXDY*DXDY);
  }
}

extern "C" void kernel_launch(void* const* d_in, const int* in_sizes, int n_in,
                              void* d_out, int out_size, void* d_ws, size_t ws_size,
                              hipStream_t stream)
{
  (void)in_sizes; (void)n_in; (void)out_size; (void)ws_size;
  const float* xy   = (const float*)d_in[0];
  const float* kW0  = (const float*)d_in[1];
  const float* kb0  = (const float*)d_in[2];
  const float* kW1  = (const float*)d_in[3];
  const float* kb1  = (const float*)d_in[4];
  const float* kW2  = (const float*)d_in[5];
  const float* kb2  = (const float*)d_in[6];
  const float* fW0  = (const float*)d_in[7];
  const float* fb0  = (const float*)d_in[8];
  const float* fW1  = (const float*)d_in[9];
  const float* fb1  = (const float*)d_in[10];
  const float* fW2  = (const float*)d_in[11];
  const float* fb2  = (const float*)d_in[12];
  const float* Wq   = (const float*)d_in[13];
  const float* bq   = (const float*)d_in[14];
  const float* Wk   = (const float*)d_in[15];
  const float* bk   = (const float*)d_in[16];
  const float* ln0g = (const float*)d_in[17];
  const float* ln0b = (const float*)d_in[18];
  const float* lng  = (const float*)d_in[19];
  const float* lnb  = (const float*)d_in[20];
  float* out = (float*)d_out;
  float* ws  = (float*)d_ws;

  float* lnp    = ws+OFF_LNP;
  float* Mg     = ws+OFF_M;
  float* ug     = ws+OFF_U;
  float* vg     = ws+OFF_V;
  float* cg     = ws+OFF_C;
  float* wsp2   = ws+OFF_WSP2;
  float* Vin    = ws+OFF_VIN;
  float* weight = ws+OFF_W;
  float* weightf= ws+OFF_WF;
  float* GPA    = ws+OFF_GPA;
  float* GSA    = ws+OFF_GSA;
  float* GPB    = ws+OFF_GPB;
  float* GSB    = ws+OFF_GSB;
  unsigned short* Wt  = (unsigned short*)(ws+OFF_P);
  unsigned short* Wft = Wt + 1048576;
  float* P1 = GPB + 524288;            // GPB upper half (lower = cross-gram)

  MlpW P = {kW0,kb0,kW1,kb1,kW2,kb2, fW0,fb0,fW1,fb1,fW2,fb2, weight, weightf};

  k_pre<<<192, 256, 0, stream>>>(xy, Wq, bq, Wk, bk, ws);
  k_ln0ag<<<602, 512, 0, stream>>>(xy, ln0g, ln0b, lnp, Vin, GPA, GSA, P, 0, ws);
  k_layer<<<597, 512, 0, stream>>>(Vin, xy, GPA, GSA, GPB, GSB,
                                   Mg, ug, vg, cg, lng, lnb, 0, 0, P, 684,
                                   Wt, Wft, wsp2, 0);
  k_layer<<<597, 512, 0, stream>>>(Vin, xy, GPB, GSB, GPA, GSA,
                                   Mg, ug, vg, cg, lng, lnb, 1, 0, P, 1366,
                                   Wt, Wft, wsp2, 0);
  // j=2: carrier (256) + 256 transpose blocks (weight final after j=1)
  k_layer<<<512, 512, 0, stream>>>(Vin, xy, GPA, GSA, GPB, GSB,
                                   Mg, ug, vg, cg, lng, lnb, 2, 1, P, 0,
                                   Wt, Wft, wsp2, 1);

  // GPA dead after j=2 -> P ns0; GPB upper -> P ns1
  k_pw<<<256, 256, 0, stream>>>(Wt, Wft, Vin, GPA, P1);
  k_final<<<256, 512, 0, stream>>>(GPB, GSB, Mg, ug, vg, cg, GPA, P1, wsp2, out);
}